// Round 4
// baseline (694.888 us; speedup 1.0000x reference)
//
#include <hip/hip_runtime.h>
#include <math.h>
#include <stdint.h>

// FrequencyAttention: B=8, L=4096, D=1024, H=16, dh=64, F=2049 (pad 2176), k=64
// Strategy: rfft(X) once; all projections commute with FFT; energy top-k via
// fp16 MFMA GEMM; sparse per-head attention (MFMA, K-split); closed-form
// sparse irfft; out GEMM. Big GEMMs: BK=32 prefetch double-buffer (T3-min),
// linear conflict-free LDS, XCD-aware block remap.

typedef _Float16 f16;
typedef _Float16 f16x8 __attribute__((ext_vector_type(8)));
typedef float f32x4 __attribute__((ext_vector_type(4)));

#define PI_F 3.14159265358979323846f

__device__ __forceinline__ void gl_lds16(const void* g, void* l) {
  __builtin_amdgcn_global_load_lds((const __attribute__((address_space(1))) void*)g,
                                   (__attribute__((address_space(3))) void*)l, 16, 0, 0);
}

// stage a 128-row x 64-byte K-slab into linear LDS [128][32] f16.
// dst must be wave-uniform; HW adds lane*16. 2 gl_lds per thread.
__device__ __forceinline__ void stage_slab(const char* gbase, size_t rowstride, int kb,
                                           char* lds, int tid, int w) {
  int s0 = tid;
  gl_lds16(gbase + (size_t)(s0 >> 2) * rowstride + kb + (s0 & 3) * 16, lds + w * 1024);
  int s1 = 256 + tid;
  gl_lds16(gbase + (size_t)(s1 >> 2) * rowstride + kb + (s1 & 3) * 16, lds + 4096 + w * 1024);
}

// ---------- prep: transpose Wq, Wo to fp16 [out][in] for MFMA B-operand ----------
__global__ __launch_bounds__(256) void k_prep(const float* __restrict__ Wq, const float* __restrict__ Wo,
                                              f16* __restrict__ WqT, f16* __restrict__ WoT) {
  __shared__ float t[32][33];
  const float* src = blockIdx.z ? Wo : Wq;
  f16* dst = blockIdx.z ? WoT : WqT;
  int c0 = blockIdx.x * 32, r0 = blockIdx.y * 32;
  int tx = threadIdx.x, ty = threadIdx.y;
#pragma unroll
  for (int yy = 0; yy < 4; ++yy)
    t[ty + yy * 8][tx] = src[(size_t)(r0 + ty + yy * 8) * 1024 + c0 + tx];
  __syncthreads();
#pragma unroll
  for (int yy = 0; yy < 4; ++yy)
    dst[(size_t)(c0 + ty + yy * 8) * 1024 + r0 + tx] = (f16)t[tx][ty + yy * 8];
}

// ---------- prep2: transpose Wk, Wv to fp16 (runs after k_fft; lives in region1 tail) ----------
__global__ __launch_bounds__(256) void k_prep2(const float* __restrict__ Wk, const float* __restrict__ Wv,
                                               f16* __restrict__ WkT, f16* __restrict__ WvT) {
  __shared__ float t[32][33];
  const float* src = blockIdx.z ? Wv : Wk;
  f16* dst = blockIdx.z ? WvT : WkT;
  int c0 = blockIdx.x * 32, r0 = blockIdx.y * 32;
  int tx = threadIdx.x, ty = threadIdx.y;
#pragma unroll
  for (int yy = 0; yy < 4; ++yy)
    t[ty + yy * 8][tx] = src[(size_t)(r0 + ty + yy * 8) * 1024 + c0 + tx];
  __syncthreads();
#pragma unroll
  for (int yy = 0; yy < 4; ++yy)
    dst[(size_t)(c0 + ty + yy * 8) * 1024 + r0 + tx] = (f16)t[tx][ty + yy * 8];
}

// ---------- transpose X (B,L,D) -> Xt (B,D,L) f32 ----------
__global__ __launch_bounds__(256) void k_t1(const float* __restrict__ X, float* __restrict__ Xt) {
  __shared__ float t[32][33];
  int b = blockIdx.z;
  int l0 = blockIdx.x * 32, d0 = blockIdx.y * 32;
  int tx = threadIdx.x, ty = threadIdx.y;
#pragma unroll
  for (int yy = 0; yy < 4; ++yy)
    t[ty + yy * 8][tx] = X[((size_t)b * 4096 + l0 + ty + yy * 8) * 1024 + d0 + tx];
  __syncthreads();
#pragma unroll
  for (int yy = 0; yy < 4; ++yy)
    Xt[((size_t)b * 1024 + d0 + ty + yy * 8) * 4096 + l0 + tx] = t[tx][ty + yy * 8];
}

// ---------- rfft(4096 real) per (b,dm) via 2048-pt complex Stockham + untangle ----------
__global__ __launch_bounds__(256) void k_fft(const float* __restrict__ Xt,
                                             f16* __restrict__ PReU, f16* __restrict__ PImU,
                                             float* __restrict__ sumXf) {
  __shared__ float ar[2048], ai[2048], br[2048], bi[2048];
  __shared__ float twr[1024], twi[1024];
  __shared__ float redr[256], redi[256];
  int tid = threadIdx.x;
  int blk = blockIdx.x;  // b*1024 + dm

  for (int k = tid; k < 1024; k += 256) {
    float ang = (float)k * (-6.28318530717958647692f / 2048.0f);
    twr[k] = cosf(ang);
    twi[k] = sinf(ang);  // e^{-2pi i k/2048}
  }
  const float4* src = (const float4*)(Xt + (size_t)blk * 4096);
#pragma unroll
  for (int r = 0; r < 4; ++r) {
    int i4 = r * 256 + tid;
    float4 v = src[i4];
    ar[2 * i4] = v.x; ai[2 * i4] = v.y;       // z[n] = x[2n] + i x[2n+1]
    ar[2 * i4 + 1] = v.z; ai[2 * i4 + 1] = v.w;
  }
  __syncthreads();
  float *cr = ar, *ci = ai, *nr = br, *ni = bi;
  for (int st = 0; st < 11; ++st) {
#pragma unroll
    for (int r = 0; r < 4; ++r) {
      int i = r * 256 + tid;           // butterfly index 0..1023
      int p = i >> st;
      int q = i & ((1 << st) - 1);
      float xr = cr[i], xi = ci[i];
      float yr = cr[i + 1024], yi = ci[i + 1024];
      float sr = xr - yr, si = xi - yi;
      int tix = p << st;               // p * (2048/ncur)
      float wr = twr[tix], wi = twi[tix];
      int o0 = q + (p << (st + 1));
      nr[o0] = xr + yr; ni[o0] = xi + yi;
      nr[o0 + (1 << st)] = sr * wr - si * wi;
      ni[o0 + (1 << st)] = sr * wi + si * wr;
    }
    __syncthreads();
    float* tp;
    tp = cr; cr = nr; nr = tp;
    tp = ci; ci = ni; ni = tp;
  }
  // untangle real FFT: X[f] = E + e^{-2pi i f/4096} * O, f = 0..2048
  float sumr = 0.f, sumi = 0.f;
  const float c2 = 6.28318530717958647692f / 4096.0f;
  size_t obase = (size_t)blk * 2049;
  for (int f = tid; f <= 2048; f += 256) {
    int fz = f & 2047, fm = (2048 - f) & 2047;
    float zr = cr[fz], zi = ci[fz], mr = cr[fm], mi = ci[fm];
    float Er = 0.5f * (zr + mr), Ei = 0.5f * (zi - mi);
    float Or = 0.5f * (zi + mi), Oi = -0.5f * (zr - mr);
    float a = c2 * (float)f;
    float wr = cosf(a), wi = -sinf(a);
    float Xr = Er + wr * Or - wi * Oi;
    float Xi = Ei + wr * Oi + wi * Or;
    PReU[obase + f] = (f16)Xr;
    PImU[obase + f] = (f16)Xi;
    sumr += Xr; sumi += Xi;
  }
  __syncthreads();
  redr[tid] = sumr; redi[tid] = sumi;
  __syncthreads();
  for (int s = 128; s > 0; s >>= 1) {
    if (tid < s) { redr[tid] += redr[tid + s]; redi[tid] += redi[tid + s]; }
    __syncthreads();
  }
  if (tid == 0) { sumXf[2 * blk] = redr[0]; sumXf[2 * blk + 1] = redi[0]; }
}

// ---------- C = mean_f(q_freq) = (sumXf @ Wq + L*bq) / F ----------
__global__ __launch_bounds__(256) void k_C(const float* __restrict__ sumXf, const float* __restrict__ Wq,
                                           const float* __restrict__ bq,
                                           float* __restrict__ Cre, float* __restrict__ Cim) {
  int b = blockIdx.x >> 2;
  int hd = ((blockIdx.x & 3) << 8) + threadIdx.x;
  float accr = 0.f, acci = 0.f;
  for (int dm = 0; dm < 1024; ++dm) {
    float w = Wq[(size_t)dm * 1024 + hd];
    accr += sumXf[2 * (b * 1024 + dm)] * w;
    acci += sumXf[2 * (b * 1024 + dm) + 1] * w;
  }
  Cre[b * 1024 + hd] = (accr + 4096.0f * bq[hd]) * (1.0f / 2049.0f);
  Cim[b * 1024 + hd] = acci * (1.0f / 2049.0f);
}

// ---------- transpose planes (B*D, 2049) -> (B, 2176, D) fp16, zero-pad ----------
__global__ __launch_bounds__(256) void k_t2(const f16* __restrict__ PReU, const f16* __restrict__ PImU,
                                            f16* __restrict__ PReT, f16* __restrict__ PImT) {
  __shared__ f16 t[32][33];
  int z = blockIdx.z;
  int b = z >> 1;
  const f16* src = (z & 1) ? PImU : PReU;
  f16* dst = (z & 1) ? PImT : PReT;
  int f0 = blockIdx.x * 32, d0 = blockIdx.y * 32;
  int tx = threadIdx.x, ty = threadIdx.y;
#pragma unroll
  for (int yy = 0; yy < 4; ++yy) {
    int ff = f0 + tx;
    t[ty + yy * 8][tx] = (ff < 2049) ? src[(size_t)(b * 1024 + d0 + ty + yy * 8) * 2049 + ff] : (f16)0.f;
  }
  __syncthreads();
#pragma unroll
  for (int yy = 0; yy < 4; ++yy)
    dst[((size_t)b * 2176 + f0 + ty + yy * 8) * 1024 + d0 + tx] = t[tx][ty + yy * 8];
}

// ---------- energy GEMM: |Xf @ Wq| head-mean, fp16 MFMA ----------
// BM=128 BN=128 BK=32, prefetch double-buffer, linear LDS (conflict-free at
// 64B rows), XCD-aware block remap.
__global__ __launch_bounds__(256) void k_energy(const f16* __restrict__ PReT, const f16* __restrict__ PImT,
                                                const f16* __restrict__ WqT, const float* __restrict__ bq,
                                                float* __restrict__ energy) {
  __shared__ __align__(16) f16 sAre[2][128 * 32];
  __shared__ __align__(16) f16 sAim[2][128 * 32];
  __shared__ __align__(16) f16 sB[2][128 * 32];
  int tid = threadIdx.x;
  int lane = tid & 63, w = tid >> 6;
  // XCD remap: all 8 N-blocks of one Mblk share lin%8 -> same XCD L2
  int lin = blockIdx.x;
  int xq = lin & 7, rq = lin >> 3;
  int bN = rq & 7;                    // 8 col-blocks of 128 (2 heads each)
  int Mblk = ((rq >> 3) << 3) + xq;   // 136 = 17*8 row tiles
  f32x4 accRe[2][8], accIm[2][8];
#pragma unroll
  for (int mf = 0; mf < 2; ++mf)
#pragma unroll
    for (int nf = 0; nf < 8; ++nf) { accRe[mf][nf] = 0; accIm[mf][nf] = 0; }

  const char* gAre0 = (const char*)PReT + (size_t)(Mblk * 128) * 2048;
  const char* gAim0 = (const char*)PImT + (size_t)(Mblk * 128) * 2048;
  const char* gB0 = (const char*)WqT + (size_t)(bN * 128) * 2048;
  int rb = w * 32;
  int r = lane & 15;
  int cby = (lane >> 4) << 4;  // byte col within 64B row

  // prologue: stage K-slab 0 into buf 0
  stage_slab(gAre0, 2048, 0, (char*)&sAre[0][0], tid, w);
  stage_slab(gAim0, 2048, 0, (char*)&sAim[0][0], tid, w);
  stage_slab(gB0, 2048, 0, (char*)&sB[0][0], tid, w);
  __syncthreads();

  for (int ks = 0; ks < 32; ++ks) {
    int cur = ks & 1;
    if (ks < 31) {  // prefetch next slab into other buffer (overlaps MFMA below)
      int kb = (ks + 1) * 64;
      stage_slab(gAre0, 2048, kb, (char*)&sAre[cur ^ 1][0], tid, w);
      stage_slab(gAim0, 2048, kb, (char*)&sAim[cur ^ 1][0], tid, w);
      stage_slab(gB0, 2048, kb, (char*)&sB[cur ^ 1][0], tid, w);
    }
    const char* bAre = (const char*)&sAre[cur][0];
    const char* bAim = (const char*)&sAim[cur][0];
    const char* bB = (const char*)&sB[cur][0];
    f16x8 aRe[2], aIm[2], bF[8];
#pragma unroll
    for (int mf = 0; mf < 2; ++mf) {
      int row = rb + mf * 16 + r;
      aRe[mf] = *(const f16x8*)(bAre + row * 64 + cby);
      aIm[mf] = *(const f16x8*)(bAim + row * 64 + cby);
    }
#pragma unroll
    for (int nf = 0; nf < 8; ++nf) {
      int row = nf * 16 + r;
      bF[nf] = *(const f16x8*)(bB + row * 64 + cby);
    }
#pragma unroll
    for (int mf = 0; mf < 2; ++mf)
#pragma unroll
      for (int nf = 0; nf < 8; ++nf) {
        accRe[mf][nf] = __builtin_amdgcn_mfma_f32_16x16x32_f16(aRe[mf], bF[nf], accRe[mf][nf], 0, 0, 0);
        accIm[mf][nf] = __builtin_amdgcn_mfma_f32_16x16x32_f16(aIm[mf], bF[nf], accIm[mf][nf], 0, 0, 0);
      }
    __syncthreads();  // drains prefetch (implicit vmcnt0) + guards buffer reuse
  }
  // epilogue: bias at f==0, |z|, mean over 64 head dims (2 heads per block)
#pragma unroll
  for (int mf = 0; mf < 2; ++mf) {
#pragma unroll
    for (int rr = 0; rr < 4; ++rr) {
      int grow = Mblk * 128 + rb + mf * 16 + ((lane >> 4) << 2) + rr;
      int bb = grow / 2176;
      int fp = grow - bb * 2176;
      float s0 = 0.f, s1 = 0.f;
#pragma unroll
      for (int nf = 0; nf < 8; ++nf) {
        float re = accRe[mf][nf][rr];
        float im = accIm[mf][nf][rr];
        if (fp == 0) re += 4096.0f * bq[bN * 128 + nf * 16 + r];
        float mag = sqrtf(re * re + im * im);
        if (nf < 4) s0 += mag; else s1 += mag;
      }
#pragma unroll
      for (int off = 1; off < 16; off <<= 1) {
        s0 += __shfl_xor(s0, off);
        s1 += __shfl_xor(s1, off);
      }
      if (r == 0) {
        energy[((size_t)bb * 16 + 2 * bN) * 2176 + fp] = s0 * 0.015625f;
        energy[((size_t)bb * 16 + 2 * bN + 1) * 2176 + fp] = s1 * 0.015625f;
      }
    }
  }
}

// ---------- top-64 per (b,h), descending, ties -> lower index ----------
__global__ __launch_bounds__(256) void k_topk(const float* __restrict__ energy, int* __restrict__ idxb) {
  __shared__ float vals[2049];
  __shared__ unsigned long long wbest[4];
  int tid = threadIdx.x, bh = blockIdx.x;
  const float* e = energy + (size_t)bh * 2176;
  for (int i = tid; i < 2049; i += 256) vals[i] = e[i];
  __syncthreads();
  for (int it = 0; it < 64; ++it) {
    unsigned long long best = 0ull;
    for (int f = tid; f < 2049; f += 256) {
      unsigned b32 = __float_as_uint(vals[f]);
      b32 = (b32 & 0x80000000u) ? ~b32 : (b32 | 0x80000000u);  // order-preserving
      unsigned long long k = ((unsigned long long)b32 << 12) | (unsigned)(4095 - f);
      best = (k > best) ? k : best;
    }
#pragma unroll
    for (int off = 32; off > 0; off >>= 1) {
      unsigned long long o = __shfl_xor(best, off);
      best = (o > best) ? o : best;
    }
    if ((tid & 63) == 0) wbest[tid >> 6] = best;
    __syncthreads();
    if (tid == 0) {
      unsigned long long b0 = wbest[0] > wbest[1] ? wbest[0] : wbest[1];
      unsigned long long b1 = wbest[2] > wbest[3] ? wbest[2] : wbest[3];
      unsigned long long bb = b0 > b1 ? b0 : b1;
      int f = 4095 - (int)(bb & 4095ull);
      idxb[bh * 64 + it] = f;
      vals[f] = -1.0f;
    }
    __syncthreads();
  }
}

// ---------- qkv GEMM: per (b,h), gathered Re rows @ [Wq|Wk|Wv] head slice ----------
__global__ __launch_bounds__(256) void k_qkv(const f16* __restrict__ PReT, const int* __restrict__ idxb,
                                             const f16* __restrict__ WqT, const f16* __restrict__ WkT,
                                             const f16* __restrict__ WvT, float* __restrict__ part) {
  __shared__ __align__(16) f16 sA[64 * 64];
  __shared__ __align__(16) f16 sB[192 * 64];
  __shared__ int fjs[64];
  int tid = threadIdx.x, lane = tid & 63, w = tid >> 6;
  int bh = blockIdx.x, ks = blockIdx.y;
  int b = bh >> 4, h = bh & 15;
  if (tid < 64) fjs[tid] = idxb[bh * 64 + tid];
  __syncthreads();
  f32x4 acc[4][3];
#pragma unroll
  for (int mf = 0; mf < 4; ++mf)
#pragma unroll
    for (int nf = 0; nf < 3; ++nf) acc[mf][nf] = 0;

  int l8 = lane & 7;   // 16B slot within 128B row
  int lr = lane >> 3;  // row within the 8-row chunk one gl_lds16 covers
  int swz = (l8 ^ lr) << 4;

  for (int kt = 0; kt < 4; ++kt) {
    int kbyte = ks * 512 + kt * 128;
#pragma unroll
    for (int t = 0; t < 2; ++t) {
      int ia = w * 2 + t;
      int row = ia * 8 + lr;
      const char* src = (const char*)PReT + (size_t)(b * 2176 + fjs[row]) * 2048 + kbyte + swz;
      gl_lds16(src, (char*)sA + ia * 1024);
    }
#pragma unroll
    for (int t = 0; t < 6; ++t) {
      int ib = w * 6 + t;
      int row = ib * 8 + lr;  // 0..191
      const f16* Wt = (row < 64) ? WqT : (row < 128) ? WkT : WvT;
      const char* src = (const char*)Wt + (size_t)(h * 64 + (row & 63)) * 2048 + kbyte + swz;
      gl_lds16(src, (char*)sB + ib * 1024);
    }
    __syncthreads();
#pragma unroll
    for (int kk = 0; kk < 64; kk += 32) {
      int cb = (kk << 1) + ((lane >> 4) << 4);
      int r = lane & 15;
      f16x8 aF[4], bF[3];
#pragma unroll
      for (int mf = 0; mf < 4; ++mf) {
        int row = mf * 16 + r;
        aF[mf] = *(const f16x8*)((const char*)sA + row * 128 + (cb ^ ((row & 7) << 4)));
      }
#pragma unroll
      for (int nf = 0; nf < 3; ++nf) {
        int row = w * 48 + nf * 16 + r;
        bF[nf] = *(const f16x8*)((const char*)sB + row * 128 + (cb ^ ((row & 7) << 4)));
      }
#pragma unroll
      for (int mf = 0; mf < 4; ++mf)
#pragma unroll
        for (int nf = 0; nf < 3; ++nf)
          acc[mf][nf] = __builtin_amdgcn_mfma_f32_16x16x32_f16(aF[mf], bF[nf], acc[mf][nf], 0, 0, 0);
    }
    __syncthreads();
  }
  // partials: part[ks][bh][m(64)][n(192)]
  float* pb = part + (size_t)(ks * 128 + bh) * 12288;
#pragma unroll
  for (int mf = 0; mf < 4; ++mf)
#pragma unroll
    for (int nf = 0; nf < 3; ++nf)
#pragma unroll
      for (int rr = 0; rr < 4; ++rr) {
        int m = mf * 16 + ((lane >> 4) << 2) + rr;
        int n = w * 48 + nf * 16 + (lane & 15);
        pb[m * 192 + n] = acc[mf][nf][rr];
      }
}

// ---------- reduce partials, bias at DC bin, scores, softmax, amp ----------
__global__ __launch_bounds__(256) void k_attn2(const float* __restrict__ part, const int* __restrict__ idxb,
                                               const float* __restrict__ bq, const float* __restrict__ bk,
                                               const float* __restrict__ bv, const float* __restrict__ Cre,
                                               float* __restrict__ amp) {
  __shared__ float sQKV[64][196];  // stride 196: 16B-aligned rows, banks spread
  __shared__ float scores[64], attns[64];
  __shared__ int fjs[64];
  __shared__ int dcrow;
  int tid = threadIdx.x, bh = blockIdx.x;
  int b = bh >> 4, h = bh & 15;
  if (tid == 0) dcrow = -1;
  __syncthreads();
  if (tid < 64) {
    int f = idxb[bh * 64 + tid];
    fjs[tid] = f;
    if (f == 0) dcrow = tid;  // bins distinct -> at most one writer
  }
  __syncthreads();
  const float4* p0 = (const float4*)(part + (size_t)bh * 12288);
  const size_t s4 = (size_t)128 * 12288 / 4;
#pragma unroll
  for (int it = 0; it < 12; ++it) {
    int e = it * 256 + tid;  // 0..3071 float4s
    float4 v0 = p0[e], v1 = p0[e + s4], v2 = p0[e + 2 * s4], v3 = p0[e + 3 * s4];
    float4 v;
    v.x = v0.x + v1.x + v2.x + v3.x;
    v.y = v0.y + v1.y + v2.y + v3.y;
    v.z = v0.z + v1.z + v2.z + v3.z;
    v.w = v0.w + v1.w + v2.w + v3.w;
    int m = e / 48, n0 = (e % 48) * 4;
    *(float4*)&sQKV[m][n0] = v;
  }
  __syncthreads();
  if (dcrow >= 0 && tid < 192) {
    const float* bias = (tid < 64) ? bq : (tid < 128) ? bk : bv;
    sQKV[dcrow][tid] += 4096.0f * bias[h * 64 + (tid & 63)];
  }
  __syncthreads();
  {
    int j = tid >> 2, p = tid & 3;
    float s = 0.f;
#pragma unroll
    for (int c = 0; c < 16; ++c) {
      int cc = p * 16 + c;
      s = fmaf(sQKV[j][cc], sQKV[j][64 + cc], s);
    }
    s += __shfl_xor(s, 1);
    s += __shfl_xor(s, 2);
    if (p == 0) scores[j] = s * 0.125f;  // / (sqrt(64)+1e-8)
  }
  __syncthreads();
  if (tid < 64) {
    float s = scores[tid];
    float m = s;
#pragma unroll
    for (int off = 32; off > 0; off >>= 1) m = fmaxf(m, __shfl_xor(m, off));
    float ev = expf(s - m);
    float sm = ev;
#pragma unroll
    for (int off = 32; off > 0; off >>= 1) sm += __shfl_xor(sm, off);
    attns[tid] = ev / sm;
  }
  __syncthreads();
  {
    int j = tid >> 2, d0 = (tid & 3) * 16;
    float at = attns[j];
    int fj = fjs[j];
    float wj = (fj == 0 || fj == 2048) ? 0.5f : 1.0f;
    float* ao = amp + ((size_t)bh * 64 + j) * 64 + d0;
#pragma unroll
    for (int q4 = 0; q4 < 4; ++q4) {
      float4 c4 = *(const float4*)&Cre[b * 1024 + h * 64 + d0 + q4 * 4];
      float4 vv = *(const float4*)&sQKV[j][128 + d0 + q4 * 4];
      float4 av;
      av.x = wj * (at * vv.x - c4.x);
      av.y = wj * (at * vv.y - c4.y);
      av.z = wj * (at * vv.z - c4.z);
      av.w = wj * (at * vv.w - c4.w);
      *(float4*)&ao[q4 * 4] = av;
    }
  }
}

// ---------- sparse irfft: out_t = [t==0]Cre + (2/L)(sum_j amp_j cos + Cim*g(t)) ----------
__global__ __launch_bounds__(256) void k_ot(const float* __restrict__ amp, const int* __restrict__ idxb,
                                            const float* __restrict__ Cre, const float* __restrict__ Cim,
                                            f16* __restrict__ OT) {
  __shared__ __align__(16) float sAmp[64][64];
  __shared__ __align__(16) float sCre[64];
  __shared__ __align__(16) float sCim[64];
  __shared__ int fjs[64];
  int tid = threadIdx.x;
  int bh = blockIdx.x >> 4, tch = blockIdx.x & 15;
  int b = bh >> 4, h = bh & 15;
  for (int e = tid; e < 4096; e += 256) ((float*)sAmp)[e] = amp[(size_t)bh * 4096 + e];
  if (tid < 64) {
    sCre[tid] = Cre[b * 1024 + h * 64 + tid];
    sCim[tid] = Cim[b * 1024 + h * 64 + tid];
    fjs[tid] = idxb[bh * 64 + tid];
  }
  __syncthreads();
  int t = tch * 256 + tid;
  float4 acc[16];
#pragma unroll
  for (int d4 = 0; d4 < 16; ++d4) acc[d4] = make_float4(0.f, 0.f, 0.f, 0.f);
  float ssum = 0.f;
  for (int jj = 0; jj < 64; ++jj) {
    int r = (fjs[jj] * t) & 4095;  // exact angle reduction: (f*t) mod L
    float ang = (float)r * 0.00153398078788564123f;  // 2*pi/4096
    float sn, cs;
    __sincosf(ang, &sn, &cs);
    ssum += sn;
    const float4* arow = (const float4*)&sAmp[jj][0];
#pragma unroll
    for (int d4 = 0; d4 < 16; ++d4) {
      float4 a = arow[d4];
      acc[d4].x = fmaf(a.x, cs, acc[d4].x);
      acc[d4].y = fmaf(a.y, cs, acc[d4].y);
      acc[d4].z = fmaf(a.z, cs, acc[d4].z);
      acc[d4].w = fmaf(a.w, cs, acc[d4].w);
    }
  }
  float g = ssum;
  if (t & 1) {  // constant-spectrum irfft contributes -(2/L)Cim*cot(pi t/L) at odd t
    int tp = (t <= 2048) ? t : 4096 - t;
    float sg = (t <= 2048) ? 1.f : -1.f;
    float aa = (float)tp * (PI_F / 4096.0f);
    g -= sg * (cosf(aa) / sinf(aa));
  }
  const float s2L = 2.0f / 4096.0f;
  int isT0 = (t == 0);
  f16* o16 = OT + ((size_t)bh * 4096 + t) * 64;
#pragma unroll
  for (int d4 = 0; d4 < 16; ++d4) {
    float4 ci4 = *(const float4*)&sCim[d4 * 4];
    float4 cr4 = *(const float4*)&sCre[d4 * 4];
    acc[d4].x = s2L * (acc[d4].x + ci4.x * g) + (isT0 ? cr4.x : 0.f);
    acc[d4].y = s2L * (acc[d4].y + ci4.y * g) + (isT0 ? cr4.y : 0.f);
    acc[d4].z = s2L * (acc[d4].z + ci4.z * g) + (isT0 ? cr4.z : 0.f);
    acc[d4].w = s2L * (acc[d4].w + ci4.w * g) + (isT0 ? cr4.w : 0.f);
  }
#pragma unroll
  for (int p = 0; p < 8; ++p) {
    float4 a = acc[2 * p], bb = acc[2 * p + 1];
    f16x8 v;
    v[0] = (f16)a.x; v[1] = (f16)a.y; v[2] = (f16)a.z; v[3] = (f16)a.w;
    v[4] = (f16)bb.x; v[5] = (f16)bb.y; v[6] = (f16)bb.z; v[7] = (f16)bb.w;
    *(f16x8*)(o16 + p * 8) = v;
  }
}

// ---------- final GEMM: out = OT(B,H,L,d as (b t) x (h d)) @ Wo + bo ----------
// BK=32 prefetch double-buffer, linear LDS, XCD-aware remap (256 Mblk = 32*8).
__global__ __launch_bounds__(256) void k_final(const f16* __restrict__ OT, const f16* __restrict__ WoT,
                                               const float* __restrict__ bo, float* __restrict__ out) {
  __shared__ __align__(16) f16 sA[2][128 * 32];
  __shared__ __align__(16) f16 sB[2][128 * 32];
  int tid = threadIdx.x, lane = tid & 63, wv = tid >> 6;
  int lin = blockIdx.x;
  int xq = lin & 7, rq = lin >> 3;
  int bN = rq & 7;
  int Mblk = ((rq >> 3) << 3) + xq;  // 256 = 32*8
  int wr = wv >> 1, wc = wv & 1;
  f32x4 acc[4][4];
#pragma unroll
  for (int mf = 0; mf < 4; ++mf)
#pragma unroll
    for (int nf = 0; nf < 4; ++nf) acc[mf][nf] = 0;
  int b = Mblk >> 5, t0 = (Mblk & 31) * 128;
  const char* gB0 = (const char*)WoT + (size_t)(bN * 128) * 2048;
  int r = lane & 15;
  int cby = (lane >> 4) << 4;

  // A slab source for K-step ks2: head = ks2>>1, byte-in-row = (ks2&1)*64
  const char* gAbase = (const char*)OT + (size_t)(b * 16) * 4096 * 128 + (size_t)t0 * 128;
#define GA_SLAB(ks2) (gAbase + (size_t)((ks2) >> 1) * 4096 * 128 + ((ks2) & 1) * 64)

  // prologue
  stage_slab(GA_SLAB(0), 128, 0, (char*)&sA[0][0], tid, wv);
  stage_slab(gB0, 2048, 0, (char*)&sB[0][0], tid, wv);
  __syncthreads();

  for (int ks2 = 0; ks2 < 32; ++ks2) {
    int cur = ks2 & 1;
    if (ks2 < 31) {
      stage_slab(GA_SLAB(ks2 + 1), 128, 0, (char*)&sA[cur ^ 1][0], tid, wv);
      stage_slab(gB0, 2048, (ks2 + 1) * 64, (char*)&sB[cur ^ 1][0], tid, wv);
    }
    const char* bA = (const char*)&sA[cur][0];
    const char* bB = (const char*)&sB[cur][0];
    f16x8 aF[4], bF[4];
#pragma unroll
    for (int mf = 0; mf < 4; ++mf) {
      int row = wr * 64 + mf * 16 + r;
      aF[mf] = *(const f16x8*)(bA + row * 64 + cby);
    }
#pragma unroll
    for (int nf = 0; nf < 4; ++nf) {
      int row = wc * 64 + nf * 16 + r;
      bF[nf] = *(const f16x8*)(bB + row * 64 + cby);
    }
#pragma unroll
    for (int mf = 0; mf < 4; ++mf)
#pragma unroll
      for (int nf = 0; nf < 4; ++nf)
        acc[mf][nf] = __builtin_amdgcn_mfma_f32_16x16x32_f16(aF[mf], bF[nf], acc[mf][nf], 0, 0, 0);
    __syncthreads();
  }
#undef GA_SLAB
#pragma unroll
  for (int nf = 0; nf < 4; ++nf) {
    int gcol = bN * 128 + wc * 64 + nf * 16 + (lane & 15);
    float bcol = bo[gcol];
#pragma unroll
    for (int mf = 0; mf < 4; ++mf) {
#pragma unroll
      for (int rr = 0; rr < 4; ++rr) {
        int grow = Mblk * 128 + wr * 64 + mf * 16 + ((lane >> 4) << 2) + rr;
        out[(size_t)grow * 1024 + gcol] = acc[mf][nf][rr] + bcol;
      }
    }
  }
}

extern "C" void kernel_launch(void* const* d_in, const int* in_sizes, int n_in,
                              void* d_out, int out_size, void* d_ws, size_t ws_size,
                              hipStream_t stream) {
  const float* X = (const float*)d_in[0];
  const float* Wq = (const float*)d_in[1];
  const float* bq = (const float*)d_in[2];
  const float* Wk = (const float*)d_in[3];
  const float* bk = (const float*)d_in[4];
  const float* Wv = (const float*)d_in[5];
  const float* bv = (const float*)d_in[6];
  const float* Wo = (const float*)d_in[7];
  const float* bo = (const float*)d_in[8];
  float* out = (float*)d_out;

  if (ws_size < 208928768ULL) return;  // workspace plan below needs ~209MB
  char* w = (char*)d_ws;
  // Region1 (0..134MB): Xt f32 (B,D,L); after FFT reused:
  //   [0..35.7M)  PReT   [35.7..71.3M) PImT
  //   [71.3M) WkT(2M) WvT(2M) part(24M)  -- written after k_fft only
  float* Xt = (float*)(w);
  f16* PReT = (f16*)(w);
  f16* PImT = (f16*)(w + 35651584);
  f16* WkT = (f16*)(w + 71303168);
  f16* WvT = (f16*)(w + 73400320);
  float* part = (float*)(w + 75497472);  // 4*128*64*192*4 = 24MB, ends < 134MB
  // Region2 (134..201MB): untransposed fp16 planes; after t2 reused for OT
  char* R2 = w + 134217728;
  f16* PReU = (f16*)(R2);
  f16* PImU = (f16*)(R2 + 33570816);
  f16* OT = (f16*)(R2);
  // Region3: small buffers
  char* R3 = R2 + 67141632;
  float* sumXf = (float*)(R3);
  float* Cre = (float*)(R3 + 65536);
  float* Cim = (float*)(R3 + 98304);
  float* energy = (float*)(R3 + 131072);
  int* idxb = (int*)(R3 + 1245184);
  float* amp = (float*)(R3 + 1277952);
  f16* WqT = (f16*)(R3 + 3375104);
  f16* WoT = (f16*)(R3 + 5472256);

  dim3 b32(32, 8);
  hipLaunchKernelGGL(k_prep, dim3(32, 32, 2), b32, 0, stream, Wq, Wo, WqT, WoT);
  hipLaunchKernelGGL(k_t1, dim3(128, 32, 8), b32, 0, stream, X, Xt);
  hipLaunchKernelGGL(k_fft, dim3(8192), dim3(256), 0, stream, Xt, PReU, PImU, sumXf);
  hipLaunchKernelGGL(k_prep2, dim3(32, 32, 2), b32, 0, stream, Wk, Wv, WkT, WvT);  // after k_fft: Xt dead
  hipLaunchKernelGGL(k_C, dim3(32), dim3(256), 0, stream, sumXf, Wq, bq, Cre, Cim);
  hipLaunchKernelGGL(k_t2, dim3(68, 32, 16), b32, 0, stream, PReU, PImU, PReT, PImT);
  hipLaunchKernelGGL(k_energy, dim3(1088), dim3(256), 0, stream, PReT, PImT, WqT, bq, energy);
  hipLaunchKernelGGL(k_topk, dim3(128), dim3(256), 0, stream, energy, idxb);
  hipLaunchKernelGGL(k_qkv, dim3(128, 4), dim3(256), 0, stream, PReT, idxb, WqT, WkT, WvT, part);
  hipLaunchKernelGGL(k_attn2, dim3(128), dim3(256), 0, stream, part, idxb, bq, bk, bv, Cre, amp);
  hipLaunchKernelGGL(k_ot, dim3(2048), dim3(256), 0, stream, amp, idxb, Cre, Cim, OT);
  hipLaunchKernelGGL(k_final, dim3(2048), dim3(256), 0, stream, OT, WoT, bo, out);
}

// Round 5
// 642.829 us; speedup vs baseline: 1.0810x; 1.0810x over previous
//
#include <hip/hip_runtime.h>
#include <math.h>
#include <stdint.h>

// FrequencyAttention: B=8, L=4096, D=1024, H=16, dh=64, F=2049 (pad 2176), k=64
// Strategy: rfft(X) once; all projections commute with FFT; energy top-k via
// ONE fp16 MFMA GEMM over an interleaved Re/Im spectrum matrix (rows 2f+z);
// sparse per-head attention (MFMA, K-split); closed-form sparse irfft; out GEMM.
// Big GEMMs use the m97 structure: 128^2 tile, BK=64, 2 tensors, swizzled LDS.

typedef _Float16 f16;
typedef _Float16 f16x8 __attribute__((ext_vector_type(8)));
typedef float f32x4 __attribute__((ext_vector_type(4)));

#define PI_F 3.14159265358979323846f

__device__ __forceinline__ void gl_lds16(const void* g, void* l) {
  __builtin_amdgcn_global_load_lds((const __attribute__((address_space(1))) void*)g,
                                   (__attribute__((address_space(3))) void*)l, 16, 0, 0);
}

// ---------- prep: transpose Wq, Wo to fp16 [out][in] for MFMA B-operand ----------
__global__ __launch_bounds__(256) void k_prep(const float* __restrict__ Wq, const float* __restrict__ Wo,
                                              f16* __restrict__ WqT, f16* __restrict__ WoT) {
  __shared__ float t[32][33];
  const float* src = blockIdx.z ? Wo : Wq;
  f16* dst = blockIdx.z ? WoT : WqT;
  int c0 = blockIdx.x * 32, r0 = blockIdx.y * 32;
  int tx = threadIdx.x, ty = threadIdx.y;
#pragma unroll
  for (int yy = 0; yy < 4; ++yy)
    t[ty + yy * 8][tx] = src[(size_t)(r0 + ty + yy * 8) * 1024 + c0 + tx];
  __syncthreads();
#pragma unroll
  for (int yy = 0; yy < 4; ++yy)
    dst[(size_t)(c0 + ty + yy * 8) * 1024 + r0 + tx] = (f16)t[tx][ty + yy * 8];
}

// ---------- prep2: transpose Wk, Wv to fp16 (runs after k_fft; lives in region1 tail) ----------
__global__ __launch_bounds__(256) void k_prep2(const float* __restrict__ Wk, const float* __restrict__ Wv,
                                               f16* __restrict__ WkT, f16* __restrict__ WvT) {
  __shared__ float t[32][33];
  const float* src = blockIdx.z ? Wv : Wk;
  f16* dst = blockIdx.z ? WvT : WkT;
  int c0 = blockIdx.x * 32, r0 = blockIdx.y * 32;
  int tx = threadIdx.x, ty = threadIdx.y;
#pragma unroll
  for (int yy = 0; yy < 4; ++yy)
    t[ty + yy * 8][tx] = src[(size_t)(r0 + ty + yy * 8) * 1024 + c0 + tx];
  __syncthreads();
#pragma unroll
  for (int yy = 0; yy < 4; ++yy)
    dst[(size_t)(c0 + ty + yy * 8) * 1024 + r0 + tx] = (f16)t[tx][ty + yy * 8];
}

// ---------- transpose X (B,L,D) -> Xt (B,D,L) f32 ----------
__global__ __launch_bounds__(256) void k_t1(const float* __restrict__ X, float* __restrict__ Xt) {
  __shared__ float t[32][33];
  int b = blockIdx.z;
  int l0 = blockIdx.x * 32, d0 = blockIdx.y * 32;
  int tx = threadIdx.x, ty = threadIdx.y;
#pragma unroll
  for (int yy = 0; yy < 4; ++yy)
    t[ty + yy * 8][tx] = X[((size_t)b * 4096 + l0 + ty + yy * 8) * 1024 + d0 + tx];
  __syncthreads();
#pragma unroll
  for (int yy = 0; yy < 4; ++yy)
    Xt[((size_t)b * 1024 + d0 + ty + yy * 8) * 4096 + l0 + tx] = t[tx][ty + yy * 8];
}

// ---------- rfft(4096 real) per (b,dm) via 2048-pt complex Stockham + untangle ----------
__global__ __launch_bounds__(256) void k_fft(const float* __restrict__ Xt,
                                             f16* __restrict__ PReU, f16* __restrict__ PImU,
                                             float* __restrict__ sumXf) {
  __shared__ float ar[2048], ai[2048], br[2048], bi[2048];
  __shared__ float twr[1024], twi[1024];
  __shared__ float redr[256], redi[256];
  int tid = threadIdx.x;
  int blk = blockIdx.x;  // b*1024 + dm

  for (int k = tid; k < 1024; k += 256) {
    float ang = (float)k * (-6.28318530717958647692f / 2048.0f);
    twr[k] = cosf(ang);
    twi[k] = sinf(ang);  // e^{-2pi i k/2048}
  }
  const float4* src = (const float4*)(Xt + (size_t)blk * 4096);
#pragma unroll
  for (int r = 0; r < 4; ++r) {
    int i4 = r * 256 + tid;
    float4 v = src[i4];
    ar[2 * i4] = v.x; ai[2 * i4] = v.y;       // z[n] = x[2n] + i x[2n+1]
    ar[2 * i4 + 1] = v.z; ai[2 * i4 + 1] = v.w;
  }
  __syncthreads();
  float *cr = ar, *ci = ai, *nr = br, *ni = bi;
  for (int st = 0; st < 11; ++st) {
#pragma unroll
    for (int r = 0; r < 4; ++r) {
      int i = r * 256 + tid;           // butterfly index 0..1023
      int p = i >> st;
      int q = i & ((1 << st) - 1);
      float xr = cr[i], xi = ci[i];
      float yr = cr[i + 1024], yi = ci[i + 1024];
      float sr = xr - yr, si = xi - yi;
      int tix = p << st;               // p * (2048/ncur)
      float wr = twr[tix], wi = twi[tix];
      int o0 = q + (p << (st + 1));
      nr[o0] = xr + yr; ni[o0] = xi + yi;
      nr[o0 + (1 << st)] = sr * wr - si * wi;
      ni[o0 + (1 << st)] = sr * wi + si * wr;
    }
    __syncthreads();
    float* tp;
    tp = cr; cr = nr; nr = tp;
    tp = ci; ci = ni; ni = tp;
  }
  // untangle real FFT: X[f] = E + e^{-2pi i f/4096} * O, f = 0..2048
  float sumr = 0.f, sumi = 0.f;
  const float c2 = 6.28318530717958647692f / 4096.0f;
  size_t obase = (size_t)blk * 2049;
  for (int f = tid; f <= 2048; f += 256) {
    int fz = f & 2047, fm = (2048 - f) & 2047;
    float zr = cr[fz], zi = ci[fz], mr = cr[fm], mi = ci[fm];
    float Er = 0.5f * (zr + mr), Ei = 0.5f * (zi - mi);
    float Or = 0.5f * (zi + mi), Oi = -0.5f * (zr - mr);
    float a = c2 * (float)f;
    float wr = cosf(a), wi = -sinf(a);
    float Xr = Er + wr * Or - wi * Oi;
    float Xi = Ei + wr * Oi + wi * Or;
    PReU[obase + f] = (f16)Xr;
    PImU[obase + f] = (f16)Xi;
    sumr += Xr; sumi += Xi;
  }
  __syncthreads();
  redr[tid] = sumr; redi[tid] = sumi;
  __syncthreads();
  for (int s = 128; s > 0; s >>= 1) {
    if (tid < s) { redr[tid] += redr[tid + s]; redi[tid] += redi[tid + s]; }
    __syncthreads();
  }
  if (tid == 0) { sumXf[2 * blk] = redr[0]; sumXf[2 * blk + 1] = redi[0]; }
}

// ---------- C = mean_f(q_freq) = (sumXf @ Wq + L*bq) / F ----------
__global__ __launch_bounds__(256) void k_C(const float* __restrict__ sumXf, const float* __restrict__ Wq,
                                           const float* __restrict__ bq,
                                           float* __restrict__ Cre, float* __restrict__ Cim) {
  int b = blockIdx.x >> 2;
  int hd = ((blockIdx.x & 3) << 8) + threadIdx.x;
  float accr = 0.f, acci = 0.f;
  for (int dm = 0; dm < 1024; ++dm) {
    float w = Wq[(size_t)dm * 1024 + hd];
    accr += sumXf[2 * (b * 1024 + dm)] * w;
    acci += sumXf[2 * (b * 1024 + dm) + 1] * w;
  }
  Cre[b * 1024 + hd] = (accr + 4096.0f * bq[hd]) * (1.0f / 2049.0f);
  Cim[b * 1024 + hd] = acci * (1.0f / 2049.0f);
}

// ---------- transpose planes (B*D, 2049) -> PT (B, 4352, D) fp16, rows 2f+z ----------
__global__ __launch_bounds__(256) void k_t2(const f16* __restrict__ PReU, const f16* __restrict__ PImU,
                                            f16* __restrict__ PT) {
  __shared__ f16 t[32][33];
  int z = blockIdx.z;
  int b = z >> 1, pl = z & 1;
  const f16* src = pl ? PImU : PReU;
  int f0 = blockIdx.x * 32, d0 = blockIdx.y * 32;
  int tx = threadIdx.x, ty = threadIdx.y;
#pragma unroll
  for (int yy = 0; yy < 4; ++yy) {
    int ff = f0 + tx;
    t[ty + yy * 8][tx] = (ff < 2049) ? src[(size_t)(b * 1024 + d0 + ty + yy * 8) * 2049 + ff] : (f16)0.f;
  }
  __syncthreads();
#pragma unroll
  for (int yy = 0; yy < 4; ++yy)
    PT[((size_t)b * 4352 + 2 * (f0 + ty + yy * 8) + pl) * 1024 + d0 + tx] = t[tx][ty + yy * 8];
}

// ---------- energy GEMM: |PT @ Wq| head-mean over interleaved Re/Im rows ----------
// m97 structure: BM=128 BN=128 BK=64, 2 tensors, 2x2 waves (64x64 tile),
// swizzled LDS (0-conflict, proven R3), XCD-aware remap. Epilogue pairs
// acc[0,1]=Re,Im of bin A and acc[2,3] of bin B in-register.
__global__ __launch_bounds__(256) void k_energy(const f16* __restrict__ PT, const f16* __restrict__ WqT,
                                                const float* __restrict__ bq, float* __restrict__ energy) {
  __shared__ __align__(16) f16 sA[128 * 64];
  __shared__ __align__(16) f16 sB[128 * 64];
  int tid = threadIdx.x;
  int lane = tid & 63, w = tid >> 6;
  // XCD remap: the 8 N-blocks of one Mblk share lin%8 -> same XCD L2
  int lin = blockIdx.x;           // 2176 = 272*8
  int xq = lin & 7, rq = lin >> 3;
  int bN = rq & 7;                // 8 col-blocks of 128 (2 heads each)
  int Mblk = ((rq >> 3) << 3) + xq;  // 0..271 row tiles (34 per batch)
  int wr = w >> 1, wc = w & 1;
  f32x4 acc[4][4];
#pragma unroll
  for (int mf = 0; mf < 4; ++mf)
#pragma unroll
    for (int nf = 0; nf < 4; ++nf) acc[mf][nf] = 0;

  const char* gA0 = (const char*)PT + (size_t)(Mblk * 128) * 2048;
  const char* gB0 = (const char*)WqT + (size_t)(bN * 128) * 2048;
  int swz = ((tid & 7) ^ ((tid >> 3) & 7)) << 4;  // pre-swizzled source 16B slot
  int r = lane & 15;
  int cq = (lane >> 4) << 4;

  for (int ks = 0; ks < 16; ++ks) {
    int kb = ks * 128;  // byte offset in K
#pragma unroll
    for (int it = 0; it < 4; ++it) {
      int row = it * 32 + (tid >> 3);
      gl_lds16(gA0 + (size_t)row * 2048 + kb + swz, (char*)sA + it * 4096 + w * 1024);
    }
#pragma unroll
    for (int it = 0; it < 4; ++it) {
      int row = it * 32 + (tid >> 3);
      gl_lds16(gB0 + (size_t)row * 2048 + kb + swz, (char*)sB + it * 4096 + w * 1024);
    }
    __syncthreads();
#pragma unroll
    for (int kk = 0; kk < 64; kk += 32) {
      int cb = (kk << 1) + cq;
      f16x8 aF[4], bF[4];
#pragma unroll
      for (int mf = 0; mf < 4; ++mf) {
        int row = wr * 64 + mf * 16 + r;
        aF[mf] = *(const f16x8*)((const char*)sA + row * 128 + (cb ^ ((row & 7) << 4)));
      }
#pragma unroll
      for (int nf = 0; nf < 4; ++nf) {
        int row = wc * 64 + nf * 16 + r;
        bF[nf] = *(const f16x8*)((const char*)sB + row * 128 + (cb ^ ((row & 7) << 4)));
      }
#pragma unroll
      for (int mf = 0; mf < 4; ++mf)
#pragma unroll
        for (int nf = 0; nf < 4; ++nf)
          acc[mf][nf] = __builtin_amdgcn_mfma_f32_16x16x32_f16(aF[mf], bF[nf], acc[mf][nf], 0, 0, 0);
    }
    __syncthreads();
  }
  // epilogue: lane quad q holds rows 4q..4q+3 -> (Re,Im) of bins base, base+1
  int b = Mblk / 34;
  int tIb = Mblk - b * 34;
  int head = 2 * bN + wc;
  int q = lane >> 4;
  bool dc = (tIb == 0 && wr == 0 && q == 0);  // global row 0 of batch = Re of f=0
#pragma unroll
  for (int mf = 0; mf < 4; ++mf) {
    float sE = 0.f, sO = 0.f;
#pragma unroll
    for (int nf = 0; nf < 4; ++nf) {
      float re0 = acc[mf][nf][0], im0 = acc[mf][nf][1];
      float re1 = acc[mf][nf][2], im1 = acc[mf][nf][3];
      if (dc && mf == 0) re0 += 4096.0f * bq[head * 64 + nf * 16 + r];
      sE += sqrtf(re0 * re0 + im0 * im0);
      sO += sqrtf(re1 * re1 + im1 * im1);
    }
#pragma unroll
    for (int off = 1; off < 16; off <<= 1) {
      sE += __shfl_xor(sE, off);
      sO += __shfl_xor(sO, off);
    }
    if (r == 0) {
      int fp = tIb * 64 + wr * 32 + mf * 8 + (q << 1);
      energy[((size_t)b * 16 + head) * 2176 + fp] = sE * 0.015625f;
      energy[((size_t)b * 16 + head) * 2176 + fp + 1] = sO * 0.015625f;
    }
  }
}

// ---------- top-64 per (b,h), descending, ties -> lower index ----------
__global__ __launch_bounds__(256) void k_topk(const float* __restrict__ energy, int* __restrict__ idxb) {
  __shared__ float vals[2049];
  __shared__ unsigned long long wbest[4];
  int tid = threadIdx.x, bh = blockIdx.x;
  const float* e = energy + (size_t)bh * 2176;
  for (int i = tid; i < 2049; i += 256) vals[i] = e[i];
  __syncthreads();
  for (int it = 0; it < 64; ++it) {
    unsigned long long best = 0ull;
    for (int f = tid; f < 2049; f += 256) {
      unsigned b32 = __float_as_uint(vals[f]);
      b32 = (b32 & 0x80000000u) ? ~b32 : (b32 | 0x80000000u);  // order-preserving
      unsigned long long k = ((unsigned long long)b32 << 12) | (unsigned)(4095 - f);
      best = (k > best) ? k : best;
    }
#pragma unroll
    for (int off = 32; off > 0; off >>= 1) {
      unsigned long long o = __shfl_xor(best, off);
      best = (o > best) ? o : best;
    }
    if ((tid & 63) == 0) wbest[tid >> 6] = best;
    __syncthreads();
    if (tid == 0) {
      unsigned long long b0 = wbest[0] > wbest[1] ? wbest[0] : wbest[1];
      unsigned long long b1 = wbest[2] > wbest[3] ? wbest[2] : wbest[3];
      unsigned long long bb = b0 > b1 ? b0 : b1;
      int f = 4095 - (int)(bb & 4095ull);
      idxb[bh * 64 + it] = f;
      vals[f] = -1.0f;
    }
    __syncthreads();
  }
}

// ---------- qkv GEMM: per (b,h), gathered Re rows @ [Wq|Wk|Wv] head slice ----------
__global__ __launch_bounds__(256) void k_qkv(const f16* __restrict__ PT, const int* __restrict__ idxb,
                                             const f16* __restrict__ WqT, const f16* __restrict__ WkT,
                                             const f16* __restrict__ WvT, float* __restrict__ part) {
  __shared__ __align__(16) f16 sA[64 * 64];
  __shared__ __align__(16) f16 sB[192 * 64];
  __shared__ int fjs[64];
  int tid = threadIdx.x, lane = tid & 63, w = tid >> 6;
  int bh = blockIdx.x, ks = blockIdx.y;
  int b = bh >> 4, h = bh & 15;
  if (tid < 64) fjs[tid] = idxb[bh * 64 + tid];
  __syncthreads();
  f32x4 acc[4][3];
#pragma unroll
  for (int mf = 0; mf < 4; ++mf)
#pragma unroll
    for (int nf = 0; nf < 3; ++nf) acc[mf][nf] = 0;

  int l8 = lane & 7;   // 16B slot within 128B row
  int lr = lane >> 3;  // row within the 8-row chunk one gl_lds16 covers
  int swz = (l8 ^ lr) << 4;

  for (int kt = 0; kt < 4; ++kt) {
    int kbyte = ks * 512 + kt * 128;
#pragma unroll
    for (int t = 0; t < 2; ++t) {
      int ia = w * 2 + t;
      int row = ia * 8 + lr;
      const char* src = (const char*)PT + (size_t)(b * 4352 + 2 * fjs[row]) * 2048 + kbyte + swz;
      gl_lds16(src, (char*)sA + ia * 1024);
    }
#pragma unroll
    for (int t = 0; t < 6; ++t) {
      int ib = w * 6 + t;
      int row = ib * 8 + lr;  // 0..191
      const f16* Wt = (row < 64) ? WqT : (row < 128) ? WkT : WvT;
      const char* src = (const char*)Wt + (size_t)(h * 64 + (row & 63)) * 2048 + kbyte + swz;
      gl_lds16(src, (char*)sB + ib * 1024);
    }
    __syncthreads();
#pragma unroll
    for (int kk = 0; kk < 64; kk += 32) {
      int cb = (kk << 1) + ((lane >> 4) << 4);
      int r = lane & 15;
      f16x8 aF[4], bF[3];
#pragma unroll
      for (int mf = 0; mf < 4; ++mf) {
        int row = mf * 16 + r;
        aF[mf] = *(const f16x8*)((const char*)sA + row * 128 + (cb ^ ((row & 7) << 4)));
      }
#pragma unroll
      for (int nf = 0; nf < 3; ++nf) {
        int row = w * 48 + nf * 16 + r;
        bF[nf] = *(const f16x8*)((const char*)sB + row * 128 + (cb ^ ((row & 7) << 4)));
      }
#pragma unroll
      for (int mf = 0; mf < 4; ++mf)
#pragma unroll
        for (int nf = 0; nf < 3; ++nf)
          acc[mf][nf] = __builtin_amdgcn_mfma_f32_16x16x32_f16(aF[mf], bF[nf], acc[mf][nf], 0, 0, 0);
    }
    __syncthreads();
  }
  // partials: part[ks][bh][m(64)][n(192)]
  float* pb = part + (size_t)(ks * 128 + bh) * 12288;
#pragma unroll
  for (int mf = 0; mf < 4; ++mf)
#pragma unroll
    for (int nf = 0; nf < 3; ++nf)
#pragma unroll
      for (int rr = 0; rr < 4; ++rr) {
        int m = mf * 16 + ((lane >> 4) << 2) + rr;
        int n = w * 48 + nf * 16 + (lane & 15);
        pb[m * 192 + n] = acc[mf][nf][rr];
      }
}

// ---------- reduce partials, bias at DC bin, scores, softmax, amp ----------
__global__ __launch_bounds__(256) void k_attn2(const float* __restrict__ part, const int* __restrict__ idxb,
                                               const float* __restrict__ bq, const float* __restrict__ bk,
                                               const float* __restrict__ bv, const float* __restrict__ Cre,
                                               float* __restrict__ amp) {
  __shared__ float sQKV[64][196];  // stride 196: 16B-aligned rows, banks spread
  __shared__ float scores[64], attns[64];
  __shared__ int fjs[64];
  __shared__ int dcrow;
  int tid = threadIdx.x, bh = blockIdx.x;
  int b = bh >> 4, h = bh & 15;
  if (tid == 0) dcrow = -1;
  __syncthreads();
  if (tid < 64) {
    int f = idxb[bh * 64 + tid];
    fjs[tid] = f;
    if (f == 0) dcrow = tid;  // bins distinct -> at most one writer
  }
  __syncthreads();
  const float4* p0 = (const float4*)(part + (size_t)bh * 12288);
  const size_t s4 = (size_t)128 * 12288 / 4;
#pragma unroll
  for (int it = 0; it < 12; ++it) {
    int e = it * 256 + tid;  // 0..3071 float4s
    float4 v0 = p0[e], v1 = p0[e + s4], v2 = p0[e + 2 * s4], v3 = p0[e + 3 * s4];
    float4 v;
    v.x = v0.x + v1.x + v2.x + v3.x;
    v.y = v0.y + v1.y + v2.y + v3.y;
    v.z = v0.z + v1.z + v2.z + v3.z;
    v.w = v0.w + v1.w + v2.w + v3.w;
    int m = e / 48, n0 = (e % 48) * 4;
    *(float4*)&sQKV[m][n0] = v;
  }
  __syncthreads();
  if (dcrow >= 0 && tid < 192) {
    const float* bias = (tid < 64) ? bq : (tid < 128) ? bk : bv;
    sQKV[dcrow][tid] += 4096.0f * bias[h * 64 + (tid & 63)];
  }
  __syncthreads();
  {
    int j = tid >> 2, p = tid & 3;
    float s = 0.f;
#pragma unroll
    for (int c = 0; c < 16; ++c) {
      int cc = p * 16 + c;
      s = fmaf(sQKV[j][cc], sQKV[j][64 + cc], s);
    }
    s += __shfl_xor(s, 1);
    s += __shfl_xor(s, 2);
    if (p == 0) scores[j] = s * 0.125f;  // / (sqrt(64)+1e-8)
  }
  __syncthreads();
  if (tid < 64) {
    float s = scores[tid];
    float m = s;
#pragma unroll
    for (int off = 32; off > 0; off >>= 1) m = fmaxf(m, __shfl_xor(m, off));
    float ev = expf(s - m);
    float sm = ev;
#pragma unroll
    for (int off = 32; off > 0; off >>= 1) sm += __shfl_xor(sm, off);
    attns[tid] = ev / sm;
  }
  __syncthreads();
  {
    int j = tid >> 2, d0 = (tid & 3) * 16;
    float at = attns[j];
    int fj = fjs[j];
    float wj = (fj == 0 || fj == 2048) ? 0.5f : 1.0f;
    float* ao = amp + ((size_t)bh * 64 + j) * 64 + d0;
#pragma unroll
    for (int q4 = 0; q4 < 4; ++q4) {
      float4 c4 = *(const float4*)&Cre[b * 1024 + h * 64 + d0 + q4 * 4];
      float4 vv = *(const float4*)&sQKV[j][128 + d0 + q4 * 4];
      float4 av;
      av.x = wj * (at * vv.x - c4.x);
      av.y = wj * (at * vv.y - c4.y);
      av.z = wj * (at * vv.z - c4.z);
      av.w = wj * (at * vv.w - c4.w);
      *(float4*)&ao[q4 * 4] = av;
    }
  }
}

// ---------- sparse irfft: out_t = [t==0]Cre + (2/L)(sum_j amp_j cos + Cim*g(t)) ----------
__global__ __launch_bounds__(256) void k_ot(const float* __restrict__ amp, const int* __restrict__ idxb,
                                            const float* __restrict__ Cre, const float* __restrict__ Cim,
                                            f16* __restrict__ OT) {
  __shared__ __align__(16) float sAmp[64][64];
  __shared__ __align__(16) float sCre[64];
  __shared__ __align__(16) float sCim[64];
  __shared__ int fjs[64];
  int tid = threadIdx.x;
  int bh = blockIdx.x >> 4, tch = blockIdx.x & 15;
  int b = bh >> 4, h = bh & 15;
  for (int e = tid; e < 4096; e += 256) ((float*)sAmp)[e] = amp[(size_t)bh * 4096 + e];
  if (tid < 64) {
    sCre[tid] = Cre[b * 1024 + h * 64 + tid];
    sCim[tid] = Cim[b * 1024 + h * 64 + tid];
    fjs[tid] = idxb[bh * 64 + tid];
  }
  __syncthreads();
  int t = tch * 256 + tid;
  float4 acc[16];
#pragma unroll
  for (int d4 = 0; d4 < 16; ++d4) acc[d4] = make_float4(0.f, 0.f, 0.f, 0.f);
  float ssum = 0.f;
  for (int jj = 0; jj < 64; ++jj) {
    int r = (fjs[jj] * t) & 4095;  // exact angle reduction: (f*t) mod L
    float ang = (float)r * 0.00153398078788564123f;  // 2*pi/4096
    float sn, cs;
    __sincosf(ang, &sn, &cs);
    ssum += sn;
    const float4* arow = (const float4*)&sAmp[jj][0];
#pragma unroll
    for (int d4 = 0; d4 < 16; ++d4) {
      float4 a = arow[d4];
      acc[d4].x = fmaf(a.x, cs, acc[d4].x);
      acc[d4].y = fmaf(a.y, cs, acc[d4].y);
      acc[d4].z = fmaf(a.z, cs, acc[d4].z);
      acc[d4].w = fmaf(a.w, cs, acc[d4].w);
    }
  }
  float g = ssum;
  if (t & 1) {  // constant-spectrum irfft contributes -(2/L)Cim*cot(pi t/L) at odd t
    int tp = (t <= 2048) ? t : 4096 - t;
    float sg = (t <= 2048) ? 1.f : -1.f;
    float aa = (float)tp * (PI_F / 4096.0f);
    g -= sg * (cosf(aa) / sinf(aa));
  }
  const float s2L = 2.0f / 4096.0f;
  int isT0 = (t == 0);
  f16* o16 = OT + ((size_t)bh * 4096 + t) * 64;
#pragma unroll
  for (int d4 = 0; d4 < 16; ++d4) {
    float4 ci4 = *(const float4*)&sCim[d4 * 4];
    float4 cr4 = *(const float4*)&sCre[d4 * 4];
    acc[d4].x = s2L * (acc[d4].x + ci4.x * g) + (isT0 ? cr4.x : 0.f);
    acc[d4].y = s2L * (acc[d4].y + ci4.y * g) + (isT0 ? cr4.y : 0.f);
    acc[d4].z = s2L * (acc[d4].z + ci4.z * g) + (isT0 ? cr4.z : 0.f);
    acc[d4].w = s2L * (acc[d4].w + ci4.w * g) + (isT0 ? cr4.w : 0.f);
  }
#pragma unroll
  for (int p = 0; p < 8; ++p) {
    float4 a = acc[2 * p], bb = acc[2 * p + 1];
    f16x8 v;
    v[0] = (f16)a.x; v[1] = (f16)a.y; v[2] = (f16)a.z; v[3] = (f16)a.w;
    v[4] = (f16)bb.x; v[5] = (f16)bb.y; v[6] = (f16)bb.z; v[7] = (f16)bb.w;
    *(f16x8*)(o16 + p * 8) = v;
  }
}

// ---------- final GEMM: out = OT(B,H,L,d as (b t) x (h d)) @ Wo + bo ----------
// m97 structure: BK=64, swizzled LDS, XCD-aware remap (256 Mblk = 32*8).
__global__ __launch_bounds__(256) void k_final(const f16* __restrict__ OT, const f16* __restrict__ WoT,
                                               const float* __restrict__ bo, float* __restrict__ out) {
  __shared__ __align__(16) f16 sA[128 * 64];
  __shared__ __align__(16) f16 sB[128 * 64];
  int tid = threadIdx.x, lane = tid & 63, wv = tid >> 6;
  int lin = blockIdx.x;
  int xq = lin & 7, rq = lin >> 3;
  int bN = rq & 7;
  int Mblk = ((rq >> 3) << 3) + xq;  // 256 = 32*8
  int wr = wv >> 1, wc = wv & 1;
  f32x4 acc[4][4];
#pragma unroll
  for (int mf = 0; mf < 4; ++mf)
#pragma unroll
    for (int nf = 0; nf < 4; ++nf) acc[mf][nf] = 0;
  int b = Mblk >> 5, t0 = (Mblk & 31) * 128;
  const char* gB0 = (const char*)WoT + (size_t)(bN * 128) * 2048;
  int swz = ((tid & 7) ^ ((tid >> 3) & 7)) << 4;
  int r = lane & 15;
  int cq = (lane >> 4) << 4;
  for (int ks = 0; ks < 16; ++ks) {  // k-step = one head's 64 dims
    const char* gA = (const char*)OT + (size_t)((b * 16 + ks) * 4096 + t0) * 128;
#pragma unroll
    for (int it = 0; it < 4; ++it) {
      int row = it * 32 + (tid >> 3);
      gl_lds16(gA + (size_t)row * 128 + swz, (char*)sA + it * 4096 + wv * 1024);
    }
    int kb = ks * 128;
#pragma unroll
    for (int it = 0; it < 4; ++it) {
      int row = it * 32 + (tid >> 3);
      gl_lds16(gB0 + (size_t)row * 2048 + kb + swz, (char*)sB + it * 4096 + wv * 1024);
    }
    __syncthreads();
#pragma unroll
    for (int kk = 0; kk < 64; kk += 32) {
      int cb = (kk << 1) + cq;
      f16x8 aF[4], bF[4];
#pragma unroll
      for (int mf = 0; mf < 4; ++mf) {
        int row = wr * 64 + mf * 16 + r;
        aF[mf] = *(const f16x8*)((const char*)sA + row * 128 + (cb ^ ((row & 7) << 4)));
      }
#pragma unroll
      for (int nf = 0; nf < 4; ++nf) {
        int row = wc * 64 + nf * 16 + r;
        bF[nf] = *(const f16x8*)((const char*)sB + row * 128 + (cb ^ ((row & 7) << 4)));
      }
#pragma unroll
      for (int mf = 0; mf < 4; ++mf)
#pragma unroll
        for (int nf = 0; nf < 4; ++nf)
          acc[mf][nf] = __builtin_amdgcn_mfma_f32_16x16x32_f16(aF[mf], bF[nf], acc[mf][nf], 0, 0, 0);
    }
    __syncthreads();
  }
#pragma unroll
  for (int nf = 0; nf < 4; ++nf) {
    int gcol = bN * 128 + wc * 64 + nf * 16 + (lane & 15);
    float bcol = bo[gcol];
#pragma unroll
    for (int mf = 0; mf < 4; ++mf) {
#pragma unroll
      for (int rr = 0; rr < 4; ++rr) {
        int grow = Mblk * 128 + wr * 64 + mf * 16 + ((lane >> 4) << 2) + rr;
        out[(size_t)grow * 1024 + gcol] = acc[mf][nf][rr] + bcol;
      }
    }
  }
}

extern "C" void kernel_launch(void* const* d_in, const int* in_sizes, int n_in,
                              void* d_out, int out_size, void* d_ws, size_t ws_size,
                              hipStream_t stream) {
  const float* X = (const float*)d_in[0];
  const float* Wq = (const float*)d_in[1];
  const float* bq = (const float*)d_in[2];
  const float* Wk = (const float*)d_in[3];
  const float* bk = (const float*)d_in[4];
  const float* Wv = (const float*)d_in[5];
  const float* bv = (const float*)d_in[6];
  const float* Wo = (const float*)d_in[7];
  const float* bo = (const float*)d_in[8];
  float* out = (float*)d_out;

  if (ws_size < 208928768ULL) return;  // workspace plan below needs ~209MB
  char* w = (char*)d_ws;
  // Region1 (0..134MB): Xt f32 (B,D,L); after FFT reused:
  //   [0..71.3M)  PT (B,4352,D) f16 interleaved Re/Im rows
  //   [71.3M) WkT(2M) WvT(2M) part(24M)  -- written after k_fft only
  float* Xt = (float*)(w);
  f16* PT = (f16*)(w);
  f16* WkT = (f16*)(w + 71303168);
  f16* WvT = (f16*)(w + 73400320);
  float* part = (float*)(w + 75497472);  // 4*128*64*192*4 = 24MB, ends < 134MB
  // Region2 (134..201MB): untransposed fp16 planes; after t2 reused for OT
  char* R2 = w + 134217728;
  f16* PReU = (f16*)(R2);
  f16* PImU = (f16*)(R2 + 33570816);
  f16* OT = (f16*)(R2);
  // Region3: small buffers
  char* R3 = R2 + 67141632;
  float* sumXf = (float*)(R3);
  float* Cre = (float*)(R3 + 65536);
  float* Cim = (float*)(R3 + 98304);
  float* energy = (float*)(R3 + 131072);
  int* idxb = (int*)(R3 + 1245184);
  float* amp = (float*)(R3 + 1277952);
  f16* WqT = (f16*)(R3 + 3375104);
  f16* WoT = (f16*)(R3 + 5472256);

  dim3 b32(32, 8);
  hipLaunchKernelGGL(k_prep, dim3(32, 32, 2), b32, 0, stream, Wq, Wo, WqT, WoT);
  hipLaunchKernelGGL(k_t1, dim3(128, 32, 8), b32, 0, stream, X, Xt);
  hipLaunchKernelGGL(k_fft, dim3(8192), dim3(256), 0, stream, Xt, PReU, PImU, sumXf);
  hipLaunchKernelGGL(k_prep2, dim3(32, 32, 2), b32, 0, stream, Wk, Wv, WkT, WvT);  // after k_fft: Xt dead
  hipLaunchKernelGGL(k_C, dim3(32), dim3(256), 0, stream, sumXf, Wq, bq, Cre, Cim);
  hipLaunchKernelGGL(k_t2, dim3(68, 32, 16), b32, 0, stream, PReU, PImU, PT);
  hipLaunchKernelGGL(k_energy, dim3(2176), dim3(256), 0, stream, PT, WqT, bq, energy);
  hipLaunchKernelGGL(k_topk, dim3(128), dim3(256), 0, stream, energy, idxb);
  hipLaunchKernelGGL(k_qkv, dim3(128, 4), dim3(256), 0, stream, PT, idxb, WqT, WkT, WvT, part);
  hipLaunchKernelGGL(k_attn2, dim3(128), dim3(256), 0, stream, part, idxb, bq, bk, bv, Cre, amp);
  hipLaunchKernelGGL(k_ot, dim3(2048), dim3(256), 0, stream, amp, idxb, Cre, Cim, OT);
  hipLaunchKernelGGL(k_final, dim3(2048), dim3(256), 0, stream, OT, WoT, bo, out);
}

// Round 6
// 584.918 us; speedup vs baseline: 1.1880x; 1.0990x over previous
//
#include <hip/hip_runtime.h>
#include <math.h>
#include <stdint.h>

// FrequencyAttention: B=8, L=4096, D=1024, H=16, dh=64, F=2049 (pad 2176), k=64
// rfft(X) once (radix-8 Stockham, table twiddles); projections commute with FFT;
// energy top-k via one fp16 MFMA GEMM over interleaved Re/Im rows; sparse
// attention (MFMA, K-split); closed-form sparse irfft; out GEMM (m97 structure).

typedef _Float16 f16;
typedef _Float16 f16x8 __attribute__((ext_vector_type(8)));
typedef float f32x4 __attribute__((ext_vector_type(4)));

#define PI_F 3.14159265358979323846f
#define PADJ(j) ((j) + ((j) >> 3))

__device__ __forceinline__ void gl_lds16(const void* g, void* l) {
  __builtin_amdgcn_global_load_lds((const __attribute__((address_space(1))) void*)g,
                                   (__attribute__((address_space(3))) void*)l, 16, 0, 0);
}

__device__ __forceinline__ float2 cadd(float2 a, float2 b) { return make_float2(a.x + b.x, a.y + b.y); }
__device__ __forceinline__ float2 csub(float2 a, float2 b) { return make_float2(a.x - b.x, a.y - b.y); }
__device__ __forceinline__ float2 cmul(float2 a, float2 b) {
  return make_float2(a.x * b.x - a.y * b.y, a.x * b.y + a.y * b.x);
}
__device__ __forceinline__ float2 cmni(float2 a) { return make_float2(a.y, -a.x); }  // a * (-i)

// ---------- twiddle tables: twtab[j]=W_2048^j, utab[f]=W_4096^f ----------
__global__ __launch_bounds__(256) void k_tw(float2* __restrict__ twtab, float2* __restrict__ utab) {
  int j = blockIdx.x * 256 + threadIdx.x;
  if (j < 2048) {
    float ang = (float)j * (-6.28318530717958647692f / 2048.0f);
    twtab[j] = make_float2(cosf(ang), sinf(ang));
  } else if (j < 4097) {
    int f = j - 2048;
    float ang = (float)f * (-6.28318530717958647692f / 4096.0f);
    utab[f] = make_float2(cosf(ang), sinf(ang));
  }
}

// ---------- prep: transpose Wq, Wo to fp16 [out][in] for MFMA B-operand ----------
__global__ __launch_bounds__(256) void k_prep(const float* __restrict__ Wq, const float* __restrict__ Wo,
                                              f16* __restrict__ WqT, f16* __restrict__ WoT) {
  __shared__ float t[32][33];
  const float* src = blockIdx.z ? Wo : Wq;
  f16* dst = blockIdx.z ? WoT : WqT;
  int c0 = blockIdx.x * 32, r0 = blockIdx.y * 32;
  int tx = threadIdx.x, ty = threadIdx.y;
#pragma unroll
  for (int yy = 0; yy < 4; ++yy)
    t[ty + yy * 8][tx] = src[(size_t)(r0 + ty + yy * 8) * 1024 + c0 + tx];
  __syncthreads();
#pragma unroll
  for (int yy = 0; yy < 4; ++yy)
    dst[(size_t)(c0 + ty + yy * 8) * 1024 + r0 + tx] = (f16)t[tx][ty + yy * 8];
}

// ---------- prep2: transpose Wk, Wv to fp16 (runs after k_fft; lives in region1 tail) ----------
__global__ __launch_bounds__(256) void k_prep2(const float* __restrict__ Wk, const float* __restrict__ Wv,
                                               f16* __restrict__ WkT, f16* __restrict__ WvT) {
  __shared__ float t[32][33];
  const float* src = blockIdx.z ? Wv : Wk;
  f16* dst = blockIdx.z ? WvT : WkT;
  int c0 = blockIdx.x * 32, r0 = blockIdx.y * 32;
  int tx = threadIdx.x, ty = threadIdx.y;
#pragma unroll
  for (int yy = 0; yy < 4; ++yy)
    t[ty + yy * 8][tx] = src[(size_t)(r0 + ty + yy * 8) * 1024 + c0 + tx];
  __syncthreads();
#pragma unroll
  for (int yy = 0; yy < 4; ++yy)
    dst[(size_t)(c0 + ty + yy * 8) * 1024 + r0 + tx] = (f16)t[tx][ty + yy * 8];
}

// ---------- transpose X (B,L,D) -> Xt (B,D,L) f32 ----------
__global__ __launch_bounds__(256) void k_t1(const float* __restrict__ X, float* __restrict__ Xt) {
  __shared__ float t[32][33];
  int b = blockIdx.z;
  int l0 = blockIdx.x * 32, d0 = blockIdx.y * 32;
  int tx = threadIdx.x, ty = threadIdx.y;
#pragma unroll
  for (int yy = 0; yy < 4; ++yy)
    t[ty + yy * 8][tx] = X[((size_t)b * 4096 + l0 + ty + yy * 8) * 1024 + d0 + tx];
  __syncthreads();
#pragma unroll
  for (int yy = 0; yy < 4; ++yy)
    Xt[((size_t)b * 1024 + d0 + ty + yy * 8) * 4096 + l0 + tx] = t[tx][ty + yy * 8];
}

// ---------- DFT8 + DIF twiddle + write (Stockham radix-8 stage) ----------
__device__ __forceinline__ void r8_stage(const float2* __restrict__ cur, float2* __restrict__ nxt,
                                         const float2* __restrict__ tw, int tid, int lg) {
  int Ls = 1 << lg;
  int p = tid >> lg, q = tid & (Ls - 1);
  float2 x[8];
#pragma unroll
  for (int u = 0; u < 8; ++u) x[u] = cur[PADJ(tid + 256 * u)];
  float2 s0 = cadd(x[0], x[4]), d0v = csub(x[0], x[4]);
  float2 s1 = cadd(x[2], x[6]), d1v = csub(x[2], x[6]);
  float2 e0 = cadd(s0, s1), e2 = csub(s0, s1);
  float2 md1 = cmni(d1v);
  float2 e1 = cadd(d0v, md1), e3 = csub(d0v, md1);
  float2 t0 = cadd(x[1], x[5]), u0 = csub(x[1], x[5]);
  float2 t1 = cadd(x[3], x[7]), u1 = csub(x[3], x[7]);
  float2 o0 = cadd(t0, t1), o2 = csub(t0, t1);
  float2 mu1 = cmni(u1);
  float2 o1 = cadd(u0, mu1), o3 = csub(u0, mu1);
  const float C8 = 0.70710678118654752440f;
  float2 w1 = make_float2(C8 * (o1.x + o1.y), C8 * (o1.y - o1.x));    // W8^1 * o1
  float2 w2 = cmni(o2);                                               // W8^2 * o2
  float2 w3 = make_float2(C8 * (o3.y - o3.x), -C8 * (o3.x + o3.y));   // W8^3 * o3
  float2 y[8];
  y[0] = cadd(e0, o0); y[4] = csub(e0, o0);
  y[1] = cadd(e1, w1); y[5] = csub(e1, w1);
  y[2] = cadd(e2, w2); y[6] = csub(e2, w2);
  y[3] = cadd(e3, w3); y[7] = csub(e3, w3);
  int tb = p << lg;
#pragma unroll
  for (int v = 1; v < 8; ++v) y[v] = cmul(y[v], tw[tb * v]);
  int ob = q + (p << (lg + 3));
#pragma unroll
  for (int v = 0; v < 8; ++v) nxt[PADJ(ob + (v << lg))] = y[v];
}

// ---------- rfft(4096 real) per (b,dm): 2048-pt radix-8 Stockham + untangle ----------
__global__ __launch_bounds__(256) void k_fft(const float* __restrict__ Xt,
                                             const float2* __restrict__ twtab,
                                             const float2* __restrict__ utab,
                                             f16* __restrict__ PReU, f16* __restrict__ PImU,
                                             float* __restrict__ sumXf) {
  __shared__ float2 bufA[2304];  // 2048 + pad
  __shared__ float2 bufB[2304];
  __shared__ float redr[256], redi[256];
  int tid = threadIdx.x;
  int blk = blockIdx.x;  // b*1024 + dm

  const float4* src = (const float4*)(Xt + (size_t)blk * 4096);
#pragma unroll
  for (int r = 0; r < 4; ++r) {
    int i4 = r * 256 + tid;
    float4 v = src[i4];
    bufA[PADJ(2 * i4)] = make_float2(v.x, v.y);      // z[n] = x[2n] + i x[2n+1]
    bufA[PADJ(2 * i4 + 1)] = make_float2(v.z, v.w);
  }
  __syncthreads();
  r8_stage(bufA, bufB, twtab, tid, 0);  // L=1
  __syncthreads();
  r8_stage(bufB, bufA, twtab, tid, 3);  // L=8
  __syncthreads();
  r8_stage(bufA, bufB, twtab, tid, 6);  // L=64
  __syncthreads();
  // final radix-4, L=512, p=0 (twiddle-free)
#pragma unroll
  for (int h = 0; h < 2; ++h) {
    int i = (h << 8) + tid;
    float2 a0 = bufB[PADJ(i)], a1 = bufB[PADJ(i + 512)];
    float2 a2 = bufB[PADJ(i + 1024)], a3 = bufB[PADJ(i + 1536)];
    float2 s02 = cadd(a0, a2), d02 = csub(a0, a2);
    float2 s13 = cadd(a1, a3), d13m = cmni(csub(a1, a3));
    bufA[PADJ(i)] = cadd(s02, s13);
    bufA[PADJ(i + 512)] = cadd(d02, d13m);
    bufA[PADJ(i + 1024)] = csub(s02, s13);
    bufA[PADJ(i + 1536)] = csub(d02, d13m);
  }
  __syncthreads();
  // untangle real FFT: X[f] = E + W_4096^f * O, f = 0..2048
  float sumr = 0.f, sumi = 0.f;
  size_t obase = (size_t)blk * 2049;
  for (int f = tid; f <= 2048; f += 256) {
    int fz = f & 2047, fm = (2048 - f) & 2047;
    float2 z = bufA[PADJ(fz)], m = bufA[PADJ(fm)];
    float Er = 0.5f * (z.x + m.x), Ei = 0.5f * (z.y - m.y);
    float Or = 0.5f * (z.y + m.y), Oi = -0.5f * (z.x - m.x);
    float2 wv = utab[f];
    float Xr = Er + wv.x * Or - wv.y * Oi;
    float Xi = Ei + wv.x * Oi + wv.y * Or;
    PReU[obase + f] = (f16)Xr;
    PImU[obase + f] = (f16)Xi;
    sumr += Xr; sumi += Xi;
  }
  __syncthreads();
  redr[tid] = sumr; redi[tid] = sumi;
  __syncthreads();
  for (int s = 128; s > 0; s >>= 1) {
    if (tid < s) { redr[tid] += redr[tid + s]; redi[tid] += redi[tid + s]; }
    __syncthreads();
  }
  if (tid == 0) { sumXf[2 * blk] = redr[0]; sumXf[2 * blk + 1] = redi[0]; }
}

// ---------- C = mean_f(q_freq) = (sumXf @ Wq + L*bq) / F ----------
__global__ __launch_bounds__(256) void k_C(const float* __restrict__ sumXf, const float* __restrict__ Wq,
                                           const float* __restrict__ bq,
                                           float* __restrict__ Cre, float* __restrict__ Cim) {
  int b = blockIdx.x >> 2;
  int hd = ((blockIdx.x & 3) << 8) + threadIdx.x;
  float accr = 0.f, acci = 0.f;
  for (int dm = 0; dm < 1024; ++dm) {
    float w = Wq[(size_t)dm * 1024 + hd];
    accr += sumXf[2 * (b * 1024 + dm)] * w;
    acci += sumXf[2 * (b * 1024 + dm) + 1] * w;
  }
  Cre[b * 1024 + hd] = (accr + 4096.0f * bq[hd]) * (1.0f / 2049.0f);
  Cim[b * 1024 + hd] = acci * (1.0f / 2049.0f);
}

// ---------- transpose planes (B*D, 2049) -> PT (B, 4352, D) fp16, rows 2f+z ----------
__global__ __launch_bounds__(256) void k_t2(const f16* __restrict__ PReU, const f16* __restrict__ PImU,
                                            f16* __restrict__ PT) {
  __shared__ f16 t[32][33];
  int z = blockIdx.z;
  int b = z >> 1, pl = z & 1;
  const f16* src = pl ? PImU : PReU;
  int f0 = blockIdx.x * 32, d0 = blockIdx.y * 32;
  int tx = threadIdx.x, ty = threadIdx.y;
#pragma unroll
  for (int yy = 0; yy < 4; ++yy) {
    int ff = f0 + tx;
    t[ty + yy * 8][tx] = (ff < 2049) ? src[(size_t)(b * 1024 + d0 + ty + yy * 8) * 2049 + ff] : (f16)0.f;
  }
  __syncthreads();
#pragma unroll
  for (int yy = 0; yy < 4; ++yy)
    PT[((size_t)b * 4352 + 2 * (f0 + ty + yy * 8) + pl) * 1024 + d0 + tx] = t[tx][ty + yy * 8];
}

// ---------- energy GEMM: |PT @ Wq| head-mean over interleaved Re/Im rows ----------
__global__ __launch_bounds__(256) void k_energy(const f16* __restrict__ PT, const f16* __restrict__ WqT,
                                                const float* __restrict__ bq, float* __restrict__ energy) {
  __shared__ __align__(16) f16 sA[128 * 64];
  __shared__ __align__(16) f16 sB[128 * 64];
  int tid = threadIdx.x;
  int lane = tid & 63, w = tid >> 6;
  int lin = blockIdx.x;           // 2176 = 272*8
  int xq = lin & 7, rq = lin >> 3;
  int bN = rq & 7;                // 8 col-blocks of 128 (2 heads each)
  int Mblk = ((rq >> 3) << 3) + xq;  // 0..271 row tiles (34 per batch)
  int wr = w >> 1, wc = w & 1;
  f32x4 acc[4][4];
#pragma unroll
  for (int mf = 0; mf < 4; ++mf)
#pragma unroll
    for (int nf = 0; nf < 4; ++nf) acc[mf][nf] = 0;

  const char* gA0 = (const char*)PT + (size_t)(Mblk * 128) * 2048;
  const char* gB0 = (const char*)WqT + (size_t)(bN * 128) * 2048;
  int swz = ((tid & 7) ^ ((tid >> 3) & 7)) << 4;
  int r = lane & 15;
  int cq = (lane >> 4) << 4;

  for (int ks = 0; ks < 16; ++ks) {
    int kb = ks * 128;
#pragma unroll
    for (int it = 0; it < 4; ++it) {
      int row = it * 32 + (tid >> 3);
      gl_lds16(gA0 + (size_t)row * 2048 + kb + swz, (char*)sA + it * 4096 + w * 1024);
    }
#pragma unroll
    for (int it = 0; it < 4; ++it) {
      int row = it * 32 + (tid >> 3);
      gl_lds16(gB0 + (size_t)row * 2048 + kb + swz, (char*)sB + it * 4096 + w * 1024);
    }
    __syncthreads();
#pragma unroll
    for (int kk = 0; kk < 64; kk += 32) {
      int cb = (kk << 1) + cq;
      f16x8 aF[4], bF[4];
#pragma unroll
      for (int mf = 0; mf < 4; ++mf) {
        int row = wr * 64 + mf * 16 + r;
        aF[mf] = *(const f16x8*)((const char*)sA + row * 128 + (cb ^ ((row & 7) << 4)));
      }
#pragma unroll
      for (int nf = 0; nf < 4; ++nf) {
        int row = wc * 64 + nf * 16 + r;
        bF[nf] = *(const f16x8*)((const char*)sB + row * 128 + (cb ^ ((row & 7) << 4)));
      }
#pragma unroll
      for (int mf = 0; mf < 4; ++mf)
#pragma unroll
        for (int nf = 0; nf < 4; ++nf)
          acc[mf][nf] = __builtin_amdgcn_mfma_f32_16x16x32_f16(aF[mf], bF[nf], acc[mf][nf], 0, 0, 0);
    }
    __syncthreads();
  }
  int b = Mblk / 34;
  int tIb = Mblk - b * 34;
  int head = 2 * bN + wc;
  int q = lane >> 4;
  bool dc = (tIb == 0 && wr == 0 && q == 0);
#pragma unroll
  for (int mf = 0; mf < 4; ++mf) {
    float sE = 0.f, sO = 0.f;
#pragma unroll
    for (int nf = 0; nf < 4; ++nf) {
      float re0 = acc[mf][nf][0], im0 = acc[mf][nf][1];
      float re1 = acc[mf][nf][2], im1 = acc[mf][nf][3];
      if (dc && mf == 0) re0 += 4096.0f * bq[head * 64 + nf * 16 + r];
      sE += sqrtf(re0 * re0 + im0 * im0);
      sO += sqrtf(re1 * re1 + im1 * im1);
    }
#pragma unroll
    for (int off = 1; off < 16; off <<= 1) {
      sE += __shfl_xor(sE, off);
      sO += __shfl_xor(sO, off);
    }
    if (r == 0) {
      int fp = tIb * 64 + wr * 32 + mf * 8 + (q << 1);
      energy[((size_t)b * 16 + head) * 2176 + fp] = sE * 0.015625f;
      energy[((size_t)b * 16 + head) * 2176 + fp + 1] = sO * 0.015625f;
    }
  }
}

// ---------- top-64 per (b,h), descending, ties -> lower index ----------
__global__ __launch_bounds__(256) void k_topk(const float* __restrict__ energy, int* __restrict__ idxb) {
  __shared__ float vals[2049];
  __shared__ unsigned long long wbest[4];
  int tid = threadIdx.x, bh = blockIdx.x;
  const float* e = energy + (size_t)bh * 2176;
  for (int i = tid; i < 2049; i += 256) vals[i] = e[i];
  __syncthreads();
  for (int it = 0; it < 64; ++it) {
    unsigned long long best = 0ull;
    for (int f = tid; f < 2049; f += 256) {
      unsigned b32 = __float_as_uint(vals[f]);
      b32 = (b32 & 0x80000000u) ? ~b32 : (b32 | 0x80000000u);
      unsigned long long k = ((unsigned long long)b32 << 12) | (unsigned)(4095 - f);
      best = (k > best) ? k : best;
    }
#pragma unroll
    for (int off = 32; off > 0; off >>= 1) {
      unsigned long long o = __shfl_xor(best, off);
      best = (o > best) ? o : best;
    }
    if ((tid & 63) == 0) wbest[tid >> 6] = best;
    __syncthreads();
    if (tid == 0) {
      unsigned long long b0 = wbest[0] > wbest[1] ? wbest[0] : wbest[1];
      unsigned long long b1 = wbest[2] > wbest[3] ? wbest[2] : wbest[3];
      unsigned long long bb = b0 > b1 ? b0 : b1;
      int f = 4095 - (int)(bb & 4095ull);
      idxb[bh * 64 + it] = f;
      vals[f] = -1.0f;
    }
    __syncthreads();
  }
}

// ---------- qkv GEMM: per (b,h), gathered Re rows @ [Wq|Wk|Wv] head slice ----------
__global__ __launch_bounds__(256) void k_qkv(const f16* __restrict__ PT, const int* __restrict__ idxb,
                                             const f16* __restrict__ WqT, const f16* __restrict__ WkT,
                                             const f16* __restrict__ WvT, float* __restrict__ part) {
  __shared__ __align__(16) f16 sA[64 * 64];
  __shared__ __align__(16) f16 sB[192 * 64];
  __shared__ int fjs[64];
  int tid = threadIdx.x, lane = tid & 63, w = tid >> 6;
  int bh = blockIdx.x, ks = blockIdx.y;
  int b = bh >> 4, h = bh & 15;
  if (tid < 64) fjs[tid] = idxb[bh * 64 + tid];
  __syncthreads();
  f32x4 acc[4][3];
#pragma unroll
  for (int mf = 0; mf < 4; ++mf)
#pragma unroll
    for (int nf = 0; nf < 3; ++nf) acc[mf][nf] = 0;

  int l8 = lane & 7;
  int lr = lane >> 3;
  int swz = (l8 ^ lr) << 4;

  for (int kt = 0; kt < 4; ++kt) {
    int kbyte = ks * 512 + kt * 128;
#pragma unroll
    for (int t = 0; t < 2; ++t) {
      int ia = w * 2 + t;
      int row = ia * 8 + lr;
      const char* src = (const char*)PT + (size_t)(b * 4352 + 2 * fjs[row]) * 2048 + kbyte + swz;
      gl_lds16(src, (char*)sA + ia * 1024);
    }
#pragma unroll
    for (int t = 0; t < 6; ++t) {
      int ib = w * 6 + t;
      int row = ib * 8 + lr;
      const f16* Wt = (row < 64) ? WqT : (row < 128) ? WkT : WvT;
      const char* src = (const char*)Wt + (size_t)(h * 64 + (row & 63)) * 2048 + kbyte + swz;
      gl_lds16(src, (char*)sB + ib * 1024);
    }
    __syncthreads();
#pragma unroll
    for (int kk = 0; kk < 64; kk += 32) {
      int cb = (kk << 1) + ((lane >> 4) << 4);
      int r = lane & 15;
      f16x8 aF[4], bF[3];
#pragma unroll
      for (int mf = 0; mf < 4; ++mf) {
        int row = mf * 16 + r;
        aF[mf] = *(const f16x8*)((const char*)sA + row * 128 + (cb ^ ((row & 7) << 4)));
      }
#pragma unroll
      for (int nf = 0; nf < 3; ++nf) {
        int row = w * 48 + nf * 16 + r;
        bF[nf] = *(const f16x8*)((const char*)sB + row * 128 + (cb ^ ((row & 7) << 4)));
      }
#pragma unroll
      for (int mf = 0; mf < 4; ++mf)
#pragma unroll
        for (int nf = 0; nf < 3; ++nf)
          acc[mf][nf] = __builtin_amdgcn_mfma_f32_16x16x32_f16(aF[mf], bF[nf], acc[mf][nf], 0, 0, 0);
    }
    __syncthreads();
  }
  float* pb = part + (size_t)(ks * 128 + bh) * 12288;
#pragma unroll
  for (int mf = 0; mf < 4; ++mf)
#pragma unroll
    for (int nf = 0; nf < 3; ++nf)
#pragma unroll
      for (int rr = 0; rr < 4; ++rr) {
        int m = mf * 16 + ((lane >> 4) << 2) + rr;
        int n = w * 48 + nf * 16 + (lane & 15);
        pb[m * 192 + n] = acc[mf][nf][rr];
      }
}

// ---------- reduce partials, bias at DC bin, scores, softmax, amp ----------
__global__ __launch_bounds__(256) void k_attn2(const float* __restrict__ part, const int* __restrict__ idxb,
                                               const float* __restrict__ bq, const float* __restrict__ bk,
                                               const float* __restrict__ bv, const float* __restrict__ Cre,
                                               float* __restrict__ amp) {
  __shared__ float sQKV[64][196];
  __shared__ float scores[64], attns[64];
  __shared__ int fjs[64];
  __shared__ int dcrow;
  int tid = threadIdx.x, bh = blockIdx.x;
  int b = bh >> 4, h = bh & 15;
  if (tid == 0) dcrow = -1;
  __syncthreads();
  if (tid < 64) {
    int f = idxb[bh * 64 + tid];
    fjs[tid] = f;
    if (f == 0) dcrow = tid;
  }
  __syncthreads();
  const float4* p0 = (const float4*)(part + (size_t)bh * 12288);
  const size_t s4 = (size_t)128 * 12288 / 4;
#pragma unroll
  for (int it = 0; it < 12; ++it) {
    int e = it * 256 + tid;
    float4 v0 = p0[e], v1 = p0[e + s4], v2 = p0[e + 2 * s4], v3 = p0[e + 3 * s4];
    float4 v;
    v.x = v0.x + v1.x + v2.x + v3.x;
    v.y = v0.y + v1.y + v2.y + v3.y;
    v.z = v0.z + v1.z + v2.z + v3.z;
    v.w = v0.w + v1.w + v2.w + v3.w;
    int m = e / 48, n0 = (e % 48) * 4;
    *(float4*)&sQKV[m][n0] = v;
  }
  __syncthreads();
  if (dcrow >= 0 && tid < 192) {
    const float* bias = (tid < 64) ? bq : (tid < 128) ? bk : bv;
    sQKV[dcrow][tid] += 4096.0f * bias[h * 64 + (tid & 63)];
  }
  __syncthreads();
  {
    int j = tid >> 2, p = tid & 3;
    float s = 0.f;
#pragma unroll
    for (int c = 0; c < 16; ++c) {
      int cc = p * 16 + c;
      s = fmaf(sQKV[j][cc], sQKV[j][64 + cc], s);
    }
    s += __shfl_xor(s, 1);
    s += __shfl_xor(s, 2);
    if (p == 0) scores[j] = s * 0.125f;
  }
  __syncthreads();
  if (tid < 64) {
    float s = scores[tid];
    float m = s;
#pragma unroll
    for (int off = 32; off > 0; off >>= 1) m = fmaxf(m, __shfl_xor(m, off));
    float ev = expf(s - m);
    float sm = ev;
#pragma unroll
    for (int off = 32; off > 0; off >>= 1) sm += __shfl_xor(sm, off);
    attns[tid] = ev / sm;
  }
  __syncthreads();
  {
    int j = tid >> 2, d0 = (tid & 3) * 16;
    float at = attns[j];
    int fj = fjs[j];
    float wj = (fj == 0 || fj == 2048) ? 0.5f : 1.0f;
    float* ao = amp + ((size_t)bh * 64 + j) * 64 + d0;
#pragma unroll
    for (int q4 = 0; q4 < 4; ++q4) {
      float4 c4 = *(const float4*)&Cre[b * 1024 + h * 64 + d0 + q4 * 4];
      float4 vv = *(const float4*)&sQKV[j][128 + d0 + q4 * 4];
      float4 av;
      av.x = wj * (at * vv.x - c4.x);
      av.y = wj * (at * vv.y - c4.y);
      av.z = wj * (at * vv.z - c4.z);
      av.w = wj * (at * vv.w - c4.w);
      *(float4*)&ao[q4 * 4] = av;
    }
  }
}

// ---------- sparse irfft: out_t = [t==0]Cre + (2/L)(sum_j amp_j cos + Cim*g(t)) ----------
__global__ __launch_bounds__(256) void k_ot(const float* __restrict__ amp, const int* __restrict__ idxb,
                                            const float* __restrict__ Cre, const float* __restrict__ Cim,
                                            f16* __restrict__ OT) {
  __shared__ __align__(16) float sAmp[64][64];
  __shared__ __align__(16) float sCre[64];
  __shared__ __align__(16) float sCim[64];
  __shared__ int fjs[64];
  int tid = threadIdx.x;
  int bh = blockIdx.x >> 4, tch = blockIdx.x & 15;
  int b = bh >> 4, h = bh & 15;
  for (int e = tid; e < 4096; e += 256) ((float*)sAmp)[e] = amp[(size_t)bh * 4096 + e];
  if (tid < 64) {
    sCre[tid] = Cre[b * 1024 + h * 64 + tid];
    sCim[tid] = Cim[b * 1024 + h * 64 + tid];
    fjs[tid] = idxb[bh * 64 + tid];
  }
  __syncthreads();
  int t = tch * 256 + tid;
  float4 acc[16];
#pragma unroll
  for (int d4 = 0; d4 < 16; ++d4) acc[d4] = make_float4(0.f, 0.f, 0.f, 0.f);
  float ssum = 0.f;
  for (int jj = 0; jj < 64; ++jj) {
    int r = (fjs[jj] * t) & 4095;
    float ang = (float)r * 0.00153398078788564123f;
    float sn, cs;
    __sincosf(ang, &sn, &cs);
    ssum += sn;
    const float4* arow = (const float4*)&sAmp[jj][0];
#pragma unroll
    for (int d4 = 0; d4 < 16; ++d4) {
      float4 a = arow[d4];
      acc[d4].x = fmaf(a.x, cs, acc[d4].x);
      acc[d4].y = fmaf(a.y, cs, acc[d4].y);
      acc[d4].z = fmaf(a.z, cs, acc[d4].z);
      acc[d4].w = fmaf(a.w, cs, acc[d4].w);
    }
  }
  float g = ssum;
  if (t & 1) {
    int tp = (t <= 2048) ? t : 4096 - t;
    float sg = (t <= 2048) ? 1.f : -1.f;
    float aa = (float)tp * (PI_F / 4096.0f);
    g -= sg * (cosf(aa) / sinf(aa));
  }
  const float s2L = 2.0f / 4096.0f;
  int isT0 = (t == 0);
  f16* o16 = OT + ((size_t)bh * 4096 + t) * 64;
#pragma unroll
  for (int d4 = 0; d4 < 16; ++d4) {
    float4 ci4 = *(const float4*)&sCim[d4 * 4];
    float4 cr4 = *(const float4*)&sCre[d4 * 4];
    acc[d4].x = s2L * (acc[d4].x + ci4.x * g) + (isT0 ? cr4.x : 0.f);
    acc[d4].y = s2L * (acc[d4].y + ci4.y * g) + (isT0 ? cr4.y : 0.f);
    acc[d4].z = s2L * (acc[d4].z + ci4.z * g) + (isT0 ? cr4.z : 0.f);
    acc[d4].w = s2L * (acc[d4].w + ci4.w * g) + (isT0 ? cr4.w : 0.f);
  }
#pragma unroll
  for (int p = 0; p < 8; ++p) {
    float4 a = acc[2 * p], bb = acc[2 * p + 1];
    f16x8 v;
    v[0] = (f16)a.x; v[1] = (f16)a.y; v[2] = (f16)a.z; v[3] = (f16)a.w;
    v[4] = (f16)bb.x; v[5] = (f16)bb.y; v[6] = (f16)bb.z; v[7] = (f16)bb.w;
    *(f16x8*)(o16 + p * 8) = v;
  }
}

// ---------- final GEMM: out = OT @ Wo + bo (m97 structure) ----------
__global__ __launch_bounds__(256) void k_final(const f16* __restrict__ OT, const f16* __restrict__ WoT,
                                               const float* __restrict__ bo, float* __restrict__ out) {
  __shared__ __align__(16) f16 sA[128 * 64];
  __shared__ __align__(16) f16 sB[128 * 64];
  int tid = threadIdx.x, lane = tid & 63, wv = tid >> 6;
  int lin = blockIdx.x;
  int xq = lin & 7, rq = lin >> 3;
  int bN = rq & 7;
  int Mblk = ((rq >> 3) << 3) + xq;
  int wr = wv >> 1, wc = wv & 1;
  f32x4 acc[4][4];
#pragma unroll
  for (int mf = 0; mf < 4; ++mf)
#pragma unroll
    for (int nf = 0; nf < 4; ++nf) acc[mf][nf] = 0;
  int b = Mblk >> 5, t0 = (Mblk & 31) * 128;
  const char* gB0 = (const char*)WoT + (size_t)(bN * 128) * 2048;
  int swz = ((tid & 7) ^ ((tid >> 3) & 7)) << 4;
  int r = lane & 15;
  int cq = (lane >> 4) << 4;
  for (int ks = 0; ks < 16; ++ks) {
    const char* gA = (const char*)OT + (size_t)((b * 16 + ks) * 4096 + t0) * 128;
#pragma unroll
    for (int it = 0; it < 4; ++it) {
      int row = it * 32 + (tid >> 3);
      gl_lds16(gA + (size_t)row * 128 + swz, (char*)sA + it * 4096 + wv * 1024);
    }
    int kb = ks * 128;
#pragma unroll
    for (int it = 0; it < 4; ++it) {
      int row = it * 32 + (tid >> 3);
      gl_lds16(gB0 + (size_t)row * 2048 + kb + swz, (char*)sB + it * 4096 + wv * 1024);
    }
    __syncthreads();
#pragma unroll
    for (int kk = 0; kk < 64; kk += 32) {
      int cb = (kk << 1) + cq;
      f16x8 aF[4], bF[4];
#pragma unroll
      for (int mf = 0; mf < 4; ++mf) {
        int row = wr * 64 + mf * 16 + r;
        aF[mf] = *(const f16x8*)((const char*)sA + row * 128 + (cb ^ ((row & 7) << 4)));
      }
#pragma unroll
      for (int nf = 0; nf < 4; ++nf) {
        int row = wc * 64 + nf * 16 + r;
        bF[nf] = *(const f16x8*)((const char*)sB + row * 128 + (cb ^ ((row & 7) << 4)));
      }
#pragma unroll
      for (int mf = 0; mf < 4; ++mf)
#pragma unroll
        for (int nf = 0; nf < 4; ++nf)
          acc[mf][nf] = __builtin_amdgcn_mfma_f32_16x16x32_f16(aF[mf], bF[nf], acc[mf][nf], 0, 0, 0);
    }
    __syncthreads();
  }
#pragma unroll
  for (int nf = 0; nf < 4; ++nf) {
    int gcol = bN * 128 + wc * 64 + nf * 16 + (lane & 15);
    float bcol = bo[gcol];
#pragma unroll
    for (int mf = 0; mf < 4; ++mf) {
#pragma unroll
      for (int rr = 0; rr < 4; ++rr) {
        int grow = Mblk * 128 + wr * 64 + mf * 16 + ((lane >> 4) << 2) + rr;
        out[(size_t)grow * 1024 + gcol] = acc[mf][nf][rr] + bcol;
      }
    }
  }
}

extern "C" void kernel_launch(void* const* d_in, const int* in_sizes, int n_in,
                              void* d_out, int out_size, void* d_ws, size_t ws_size,
                              hipStream_t stream) {
  const float* X = (const float*)d_in[0];
  const float* Wq = (const float*)d_in[1];
  const float* bq = (const float*)d_in[2];
  const float* Wk = (const float*)d_in[3];
  const float* bk = (const float*)d_in[4];
  const float* Wv = (const float*)d_in[5];
  const float* bv = (const float*)d_in[6];
  const float* Wo = (const float*)d_in[7];
  const float* bo = (const float*)d_in[8];
  float* out = (float*)d_out;

  if (ws_size < 208928768ULL) return;
  char* w = (char*)d_ws;
  // Region1 (0..134MB): Xt f32 (B,D,L); after FFT reused:
  //   [0..71.3M) PT (B,4352,D) f16 interleaved; [71.3M) WkT WvT part
  float* Xt = (float*)(w);
  f16* PT = (f16*)(w);
  f16* WkT = (f16*)(w + 71303168);
  f16* WvT = (f16*)(w + 73400320);
  float* part = (float*)(w + 75497472);
  // Region2 (134..201MB): untransposed fp16 planes; after t2 reused for OT
  char* R2 = w + 134217728;
  f16* PReU = (f16*)(R2);
  f16* PImU = (f16*)(R2 + 33570816);
  f16* OT = (f16*)(R2);
  // Region3: small buffers
  char* R3 = R2 + 67141632;
  float* sumXf = (float*)(R3);
  float* Cre = (float*)(R3 + 65536);
  float* Cim = (float*)(R3 + 98304);
  float* energy = (float*)(R3 + 131072);
  int* idxb = (int*)(R3 + 1245184);
  float* amp = (float*)(R3 + 1277952);
  f16* WqT = (f16*)(R3 + 3375104);
  f16* WoT = (f16*)(R3 + 5472256);
  // FFT tables live in d_out's head: dead until k_final, which overwrites all
  // of d_out (Mblk covers rows [0,32768), bN covers cols [0,1024)).
  float2* twtab = (float2*)d_out;
  float2* utab = twtab + 2048;

  dim3 b32(32, 8);
  hipLaunchKernelGGL(k_tw, dim3(17), dim3(256), 0, stream, twtab, utab);
  hipLaunchKernelGGL(k_prep, dim3(32, 32, 2), b32, 0, stream, Wq, Wo, WqT, WoT);
  hipLaunchKernelGGL(k_t1, dim3(128, 32, 8), b32, 0, stream, X, Xt);
  hipLaunchKernelGGL(k_fft, dim3(8192), dim3(256), 0, stream, Xt, twtab, utab, PReU, PImU, sumXf);
  hipLaunchKernelGGL(k_prep2, dim3(32, 32, 2), b32, 0, stream, Wk, Wv, WkT, WvT);
  hipLaunchKernelGGL(k_C, dim3(32), dim3(256), 0, stream, sumXf, Wq, bq, Cre, Cim);
  hipLaunchKernelGGL(k_t2, dim3(68, 32, 16), b32, 0, stream, PReU, PImU, PT);
  hipLaunchKernelGGL(k_energy, dim3(2176), dim3(256), 0, stream, PT, WqT, bq, energy);
  hipLaunchKernelGGL(k_topk, dim3(128), dim3(256), 0, stream, energy, idxb);
  hipLaunchKernelGGL(k_qkv, dim3(128, 4), dim3(256), 0, stream, PT, idxb, WqT, WkT, WvT, part);
  hipLaunchKernelGGL(k_attn2, dim3(128), dim3(256), 0, stream, part, idxb, bq, bk, bv, Cre, amp);
  hipLaunchKernelGGL(k_ot, dim3(2048), dim3(256), 0, stream, amp, idxb, Cre, Cim, OT);
  hipLaunchKernelGGL(k_final, dim3(2048), dim3(256), 0, stream, OT, WoT, bo, out);
}